// Round 11
// baseline (175.065 us; speedup 1.0000x reference)
//
#include <hip/hip_runtime.h>
#include <hip/hip_fp16.h>

// GCN 2-layer forward. CSR via two-phase dst-sort (coalesced writes),
// MFMA fp16 GEMMs (fp32 accum), fp16 message tables, gather aggregation.
// R11: chunksort CHUNK 4096->1024 (occupancy 11%->~40%), bucketsort 512 thr.

#define CHUNK 1024
#define BCAP  4096
#define NB_PAD 1024

typedef _Float16 f16x8 __attribute__((ext_vector_type(8)));
typedef float f32x4 __attribute__((ext_vector_type(4)));

__device__ __forceinline__ unsigned int pack2(float a, float b) {
  __half2 h = __floats2half2_rn(a, b);
  return *reinterpret_cast<unsigned int*>(&h);
}
__device__ __forceinline__ __half2 h2add(__half2 a, __half2 b) {
  return __hadd2(a, b);
}
__device__ __forceinline__ __half2 bcast_h2(unsigned int u) {
  return *reinterpret_cast<__half2*>(&u);
}

__global__ __launch_bounds__(256) void initcur_kernel(int* __restrict__ bcursor,
                                                      int nb) {
  int i = blockIdx.x * 256 + threadIdx.x;
  if (i < nb) bcursor[i] = i * BCAP;
}

// Phase 1: group edges by bucket b = dst>>7 into bucket-major ebuck.
__global__ __launch_bounds__(256) void chunksort_kernel(
    const int* __restrict__ src, const int* __restrict__ dst,
    int* __restrict__ bcursor, int* __restrict__ ebuck, int nE, int nb) {
  __shared__ int hist[NB_PAD];
  __shared__ int loff[NB_PAD];
  __shared__ int gbase[NB_PAD];
  __shared__ int lcur[NB_PAD];
  __shared__ int part[256];
  __shared__ int srec[CHUNK];
  __shared__ int saddr[CHUNK];
  const int t = threadIdx.x;
  const int e0 = blockIdx.x * CHUNK;
  const int n = min(CHUNK, nE - e0);
#pragma unroll
  for (int i = t; i < NB_PAD; i += 256) hist[i] = 0;
  __syncthreads();
  for (int i = t; i < n; i += 256) atomicAdd(&hist[dst[e0 + i] >> 7], 1);
  __syncthreads();
  int h0 = hist[4 * t], h1 = hist[4 * t + 1], h2 = hist[4 * t + 2], h3 = hist[4 * t + 3];
  part[t] = h0 + h1 + h2 + h3;
  __syncthreads();
  for (int off = 1; off < 256; off <<= 1) {
    int v = (t >= off) ? part[t - off] : 0;
    __syncthreads();
    part[t] += v;
    __syncthreads();
  }
  int base = (t == 0) ? 0 : part[t - 1];
  loff[4 * t] = base;
  loff[4 * t + 1] = base + h0;
  loff[4 * t + 2] = base + h0 + h1;
  loff[4 * t + 3] = base + h0 + h1 + h2;
  __syncthreads();
  for (int b = t; b < nb; b += 256) {
    int c = hist[b];
    gbase[b] = c ? atomicAdd(&bcursor[b], c) : 0;
    lcur[b] = loff[b];
  }
  __syncthreads();
  for (int i = t; i < n; i += 256) {
    int d = dst[e0 + i];
    int b = d >> 7;
    int p = atomicAdd(&lcur[b], 1);
    srec[p] = src[e0 + i] | ((d & 127) << 17);
    saddr[p] = gbase[b] + (p - loff[b]);
  }
  __syncthreads();
  for (int i = t; i < n; i += 256) ebuck[saddr[i]] = srec[i];
}

__global__ __launch_bounds__(1024) void bscan_kernel(const int* __restrict__ bcursor,
                                                     int* __restrict__ bbase, int nb) {
  __shared__ int part[1024];
  const int t = threadIdx.x;
  int c = (t < nb) ? (bcursor[t] - t * BCAP) : 0;
  part[t] = c;
  __syncthreads();
  for (int off = 1; off < 1024; off <<= 1) {
    int v = (t >= off) ? part[t - off] : 0;
    __syncthreads();
    part[t] += v;
    __syncthreads();
  }
  if (t < nb) bbase[t] = part[t] - c;  // exclusive
}

// Phase 2: per-bucket counting sort -> fully dst-sorted esrc + rowptr + dinv.
__global__ __launch_bounds__(512) void bucketsort_kernel(
    const int* __restrict__ ebuck, const int* __restrict__ bcursor,
    const int* __restrict__ bbase, int* __restrict__ esrc,
    int* __restrict__ rowptr, float* __restrict__ dinv, int N, int E, int nb) {
  __shared__ int hist[128];
  __shared__ int sc[128];
  __shared__ int rowcur[128];
  __shared__ int ssrc[BCAP];
  const int t = threadIdx.x;
  const int bk = blockIdx.x;
  const int base = bk * BCAP;
  const int cnt = bcursor[bk] - base;
  const int gb = bbase[bk];
  if (t < 128) hist[t] = 0;
  __syncthreads();
  for (int i = t; i < cnt; i += 512)
    atomicAdd(&hist[(ebuck[base + i] >> 17) & 127], 1);
  __syncthreads();
  if (t < 128) sc[t] = hist[t];
  __syncthreads();
  for (int off = 1; off < 128; off <<= 1) {
    int v = 0;
    if (t < 128 && t >= off) v = sc[t - off];
    __syncthreads();
    if (t < 128) sc[t] += v;
    __syncthreads();
  }
  if (t < 128) {
    int excl = (t == 0) ? 0 : sc[t - 1];
    rowcur[t] = excl;
    int node = bk * 128 + t;
    if (node < N) {
      rowptr[node] = gb + excl;
      dinv[node] = rsqrtf((float)hist[t] + 1.0f);
    }
  }
  if (bk == nb - 1 && t == 0) rowptr[N] = E;
  __syncthreads();
  for (int i = t; i < cnt; i += 512) {
    int rec = ebuck[base + i];
    int p = atomicAdd(&rowcur[(rec >> 17) & 127], 1);
    ssrc[p] = rec & 0x1FFFF;
  }
  __syncthreads();
  for (int i = t; i < cnt; i += 512) esrc[gb + i] = ssrc[i];
}

// H[N,64](fp16) = (X[N,K] @ W[K,64]) * dinv[row], via mfma_f32_16x16x32_f16.
template <int K, bool IN_HALF>
__global__ __launch_bounds__(256) void gemm_mfma(const void* __restrict__ Xin,
                                                 const float* __restrict__ W,
                                                 const float* __restrict__ dinv,
                                                 __half* __restrict__ H, int N) {
  __shared__ __align__(16) unsigned char sA[128 * K * 2];
  __shared__ __align__(16) unsigned char sB[64 * K * 2];
  const int t = threadIdx.x;
  const int brow = blockIdx.x * 128;
  constexpr int CH = K / 8;
  for (int idx = t; idx < 128 * CH; idx += 256) {
    int r = idx / CH, c = idx - r * CH;
    int row = brow + r;
    if (row >= N) row = N - 1;
    unsigned int off = (unsigned int)((r * K + c * 8) * 2) ^ ((r & 7) << 4);
    uint4 pk;
    if constexpr (IN_HALF) {
      pk = *reinterpret_cast<const uint4*>((const __half*)Xin + (size_t)row * K + c * 8);
    } else {
      const float4* xp =
          reinterpret_cast<const float4*>((const float*)Xin + (size_t)row * K + c * 8);
      float4 f0 = xp[0], f1 = xp[1];
      pk.x = pack2(f0.x, f0.y);
      pk.y = pack2(f0.z, f0.w);
      pk.z = pack2(f1.x, f1.y);
      pk.w = pack2(f1.z, f1.w);
    }
    *reinterpret_cast<uint4*>(sA + off) = pk;
  }
  for (int idx = t; idx < K * 64; idx += 256) {
    int k = idx >> 6, n = idx & 63;
    __half h = __float2half_rn(W[idx]);
    unsigned int off = (unsigned int)((n * K + k) * 2) ^ ((n & 7) << 4);
    *reinterpret_cast<unsigned short*>(sB + off) =
        *reinterpret_cast<unsigned short*>(&h);
  }
  __syncthreads();

  const int wv = t >> 6, l = t & 63;
  const int lr = l & 15;
  const int lk = (l >> 4) * 8;
  f32x4 acc[2][4] = {};
#pragma unroll
  for (int ks = 0; ks < K / 32; ++ks) {
    f16x8 af[2], bf[4];
#pragma unroll
    for (int m = 0; m < 2; ++m) {
      int r = wv * 32 + m * 16 + lr;
      unsigned int off = (unsigned int)((r * K + ks * 32 + lk) * 2) ^ ((r & 7) << 4);
      af[m] = *reinterpret_cast<const f16x8*>(sA + off);
    }
#pragma unroll
    for (int n = 0; n < 4; ++n) {
      int cc = n * 16 + lr;
      unsigned int off = (unsigned int)((cc * K + ks * 32 + lk) * 2) ^ ((cc & 7) << 4);
      bf[n] = *reinterpret_cast<const f16x8*>(sB + off);
    }
#pragma unroll
    for (int m = 0; m < 2; ++m)
#pragma unroll
      for (int n = 0; n < 4; ++n)
        acc[m][n] = __builtin_amdgcn_mfma_f32_16x16x32_f16(af[m], bf[n], acc[m][n],
                                                           0, 0, 0);
  }
#pragma unroll
  for (int m = 0; m < 2; ++m) {
#pragma unroll
    for (int j = 0; j < 4; ++j) {
      int row = brow + wv * 32 + m * 16 + (l >> 4) * 4 + j;
      if (row < N) {
        float di = dinv[row];
#pragma unroll
        for (int n = 0; n < 4; ++n) {
          float v = acc[m][n][j] * di;
          H[(size_t)row * 64 + n * 16 + lr] = __float2half_rn(v);
        }
      }
    }
  }
}

// 4 nodes per wave: nid=lane>>4 (node), g=(lane>>3)&1 (edge group),
// cl=lane&7 (16B slice of 128B row). Per iteration: 4 wave-level uint4
// gathers (8 edges each, 2 per node), 4 independent streams.
template <bool RELU, bool OUT_HALF>
__global__ __launch_bounds__(256) void agg_kernel(const __half* __restrict__ hs,
                                                  const int* __restrict__ rowptr,
                                                  const int* __restrict__ esrc,
                                                  const float* __restrict__ dinv,
                                                  const float* __restrict__ b,
                                                  void* __restrict__ outv, int N) {
  const int wv = threadIdx.x >> 6;
  const int lane = threadIdx.x & 63;
  const int nid = lane >> 4;
  const int g = (lane >> 3) & 1;
  const int cl = lane & 7;
  const int node = blockIdx.x * 16 + wv * 4 + nid;
  const unsigned int choff = (unsigned int)cl << 4;
  const unsigned char* __restrict__ hb = (const unsigned char*)hs;
  int beg = 0, end = 0;
  if (node < N) {
    beg = rowptr[node];
    end = rowptr[node + 1];
  }
  __half2 accA[4] = {{0.f, 0.f}, {0.f, 0.f}, {0.f, 0.f}, {0.f, 0.f}};
  __half2 accB[4] = {{0.f, 0.f}, {0.f, 0.f}, {0.f, 0.f}, {0.f, 0.f}};
  int k = beg + g;
  while (k < end) {
    int s0 = esrc[min(k,     end - 1)];
    int s1 = esrc[min(k + 2, end - 1)];
    int s2 = esrc[min(k + 4, end - 1)];
    int s3 = esrc[min(k + 6, end - 1)];
    uint4 v0 = *reinterpret_cast<const uint4*>(hb + (((unsigned int)s0 << 7) + choff));
    uint4 v1 = *reinterpret_cast<const uint4*>(hb + (((unsigned int)s1 << 7) + choff));
    uint4 v2 = *reinterpret_cast<const uint4*>(hb + (((unsigned int)s2 << 7) + choff));
    uint4 v3 = *reinterpret_cast<const uint4*>(hb + (((unsigned int)s3 << 7) + choff));
    {
      accA[0] = h2add(accA[0], bcast_h2(v0.x));
      accA[1] = h2add(accA[1], bcast_h2(v0.y));
      accA[2] = h2add(accA[2], bcast_h2(v0.z));
      accA[3] = h2add(accA[3], bcast_h2(v0.w));
    }
    if (k + 2 < end) {
      accB[0] = h2add(accB[0], bcast_h2(v1.x));
      accB[1] = h2add(accB[1], bcast_h2(v1.y));
      accB[2] = h2add(accB[2], bcast_h2(v1.z));
      accB[3] = h2add(accB[3], bcast_h2(v1.w));
    }
    if (k + 4 < end) {
      accA[0] = h2add(accA[0], bcast_h2(v2.x));
      accA[1] = h2add(accA[1], bcast_h2(v2.y));
      accA[2] = h2add(accA[2], bcast_h2(v2.z));
      accA[3] = h2add(accA[3], bcast_h2(v2.w));
    }
    if (k + 6 < end) {
      accB[0] = h2add(accB[0], bcast_h2(v3.x));
      accB[1] = h2add(accB[1], bcast_h2(v3.y));
      accB[2] = h2add(accB[2], bcast_h2(v3.z));
      accB[3] = h2add(accB[3], bcast_h2(v3.w));
    }
    k += 8;
  }
#pragma unroll
  for (int r = 0; r < 4; ++r) accA[r] = h2add(accA[r], accB[r]);
#pragma unroll
  for (int r = 0; r < 4; ++r) {
    int u = __shfl_xor(*reinterpret_cast<int*>(&accA[r]), 8);
    accA[r] = h2add(accA[r], *reinterpret_cast<__half2*>(&u));
  }
  if (g == 0 && node < N) {
    uint4 sv = *reinterpret_cast<const uint4*>(hb + (((unsigned int)node << 7) + choff));
    float di = dinv[node];
    const float4* bv = reinterpret_cast<const float4*>(b);
    float4 b0 = bv[cl * 2], b1 = bv[cl * 2 + 1];
    float r[8];
#pragma unroll
    for (int q = 0; q < 4; ++q) {
      float2 av = __half22float2(accA[q]);
      float2 sf = __half22float2(bcast_h2((&sv.x)[q]));
      r[2 * q]     = (av.x + sf.x) * di;
      r[2 * q + 1] = (av.y + sf.y) * di;
    }
    r[0] += b0.x; r[1] += b0.y; r[2] += b0.z; r[3] += b0.w;
    r[4] += b1.x; r[5] += b1.y; r[6] += b1.z; r[7] += b1.w;
    if (RELU) {
#pragma unroll
      for (int q = 0; q < 8; ++q) r[q] = fmaxf(r[q], 0.f);
    }
    if constexpr (OUT_HALF) {
      uint4 pk;
      pk.x = pack2(r[0], r[1]);
      pk.y = pack2(r[2], r[3]);
      pk.z = pack2(r[4], r[5]);
      pk.w = pack2(r[6], r[7]);
      reinterpret_cast<uint4*>(outv)[(size_t)node * 8 + cl] = pk;
    } else {
      float4* ov = reinterpret_cast<float4*>(outv);
      ov[(size_t)node * 16 + cl * 2]     = make_float4(r[0], r[1], r[2], r[3]);
      ov[(size_t)node * 16 + cl * 2 + 1] = make_float4(r[4], r[5], r[6], r[7]);
    }
  }
}

extern "C" void kernel_launch(void* const* d_in, const int* in_sizes, int n_in,
                              void* d_out, int out_size, void* d_ws, size_t ws_size,
                              hipStream_t stream) {
  const float* x  = (const float*)d_in[0];
  const int*   ei = (const int*)d_in[1];
  const float* W1 = (const float*)d_in[2];
  const float* b1 = (const float*)d_in[3];
  const float* W2 = (const float*)d_in[4];
  const float* b2 = (const float*)d_in[5];
  const int N = in_sizes[0] / 128;
  const int E = in_sizes[1] / 2;
  const int* src = ei;
  const int* dst = ei + E;
  const int nb = (N + 127) >> 7;  // 782 buckets

  char* ws = (char*)d_ws;
  int*    bcursor = (int*)ws;                       // nb ints
  int*    bbase   = (int*)(ws + (1 << 19));         // nb ints   @ 512KB
  float*  dinv    = (float*)(ws + (1 << 20));       // N floats  @ 1MB
  int*    rowptr  = (int*)(ws + 3 * (1 << 19));     // N+1 ints  @ 1.5MB
  int*    esrc    = (int*)(ws + (1 << 21));         // E ints    @ 2MB   (6.4MB)
  int*    ebuck   = (int*)(ws + 9 * (1 << 20));     // nb*BCAP   @ 9MB   (12.8MB)
  __half* hs      = (__half*)(ws + 22 * (1 << 20)); // N*64 fp16 @ 22MB  (12.8MB)
  __half* y1h     = (__half*)(ws + 36 * (1 << 20)); // N*64 fp16 @ 36MB  (12.8MB)
  float*  out = (float*)d_out;

  // CSR build (shared by both layers)
  initcur_kernel<<<(nb + 255) / 256, 256, 0, stream>>>(bcursor, nb);
  chunksort_kernel<<<(E + CHUNK - 1) / CHUNK, 256, 0, stream>>>(src, dst, bcursor,
                                                                ebuck, E, nb);
  bscan_kernel<<<1, 1024, 0, stream>>>(bcursor, bbase, nb);
  bucketsort_kernel<<<nb, 512, 0, stream>>>(ebuck, bcursor, bbase, esrc, rowptr,
                                            dinv, N, E, nb);

  const int gemmGrid = (N + 127) / 128;
  const int aggGrid = (N + 15) / 16;
  // layer 1: hs1(fp16) -> hs ; y1(fp16, relu) -> y1h
  gemm_mfma<128, false><<<gemmGrid, 256, 0, stream>>>(x, W1, dinv, hs, N);
  agg_kernel<true, true><<<aggGrid, 256, 0, stream>>>(hs, rowptr, esrc, dinv, b1,
                                                      y1h, N);
  // layer 2: hs2(fp16) -> hs (reuse) ; y2(fp32) -> out
  gemm_mfma<64, true><<<gemmGrid, 256, 0, stream>>>(y1h, W2, dinv, hs, N);
  agg_kernel<false, false><<<aggGrid, 256, 0, stream>>>(hs, rowptr, esrc, dinv, b2,
                                                        out, N);
}

// Round 12
// 144.171 us; speedup vs baseline: 1.2143x; 1.2143x over previous
//
#include <hip/hip_runtime.h>
#include <hip/hip_fp16.h>

// GCN 2-layer forward. CSR via two-phase dst-sort, MFMA fp16 GEMMs,
// fp16 message tables, 4-node-per-wave gather aggregation.
// R12: 256-node buckets (nb=391). chunksort CHUNK=2048/512thr (26KB LDS,
// 2 blocks/CU). bucketsort: direct-global scatter (3KB LDS, 1024thr).

#define CHUNK 2048
#define BCAP  8192
#define NB_PAD 512
#define BSHIFT 8
#define BMASK 255

typedef _Float16 f16x8 __attribute__((ext_vector_type(8)));
typedef float f32x4 __attribute__((ext_vector_type(4)));

__device__ __forceinline__ unsigned int pack2(float a, float b) {
  __half2 h = __floats2half2_rn(a, b);
  return *reinterpret_cast<unsigned int*>(&h);
}
__device__ __forceinline__ __half2 h2add(__half2 a, __half2 b) {
  return __hadd2(a, b);
}
__device__ __forceinline__ __half2 bcast_h2(unsigned int u) {
  return *reinterpret_cast<__half2*>(&u);
}

__global__ __launch_bounds__(256) void initcur_kernel(int* __restrict__ bcursor,
                                                      int nb) {
  int i = blockIdx.x * 256 + threadIdx.x;
  if (i < nb) bcursor[i] = i * BCAP;
}

// Phase 1: group edges by bucket b = dst>>8 into bucket-major ebuck.
// Record = src | (dst&255)<<17.  Run-contiguous global writes from LDS sort.
__global__ __launch_bounds__(512) void chunksort_kernel(
    const int* __restrict__ src, const int* __restrict__ dst,
    int* __restrict__ bcursor, int* __restrict__ ebuck, int nE, int nb) {
  __shared__ int hist[NB_PAD];
  __shared__ int loff[NB_PAD];
  __shared__ int gbase[NB_PAD];
  __shared__ int lcur[NB_PAD];
  __shared__ int part[NB_PAD];
  __shared__ int srec[CHUNK];
  __shared__ int saddr[CHUNK];
  const int t = threadIdx.x;
  const int e0 = blockIdx.x * CHUNK;
  const int n = min(CHUNK, nE - e0);
  hist[t] = 0;
  __syncthreads();
  for (int i = t; i < n; i += 512) atomicAdd(&hist[dst[e0 + i] >> BSHIFT], 1);
  __syncthreads();
  part[t] = hist[t];
  __syncthreads();
  for (int off = 1; off < NB_PAD; off <<= 1) {   // Hillis inclusive over 512
    int v = (t >= off) ? part[t - off] : 0;
    __syncthreads();
    part[t] += v;
    __syncthreads();
  }
  int excl = (t == 0) ? 0 : part[t - 1];
  loff[t] = excl;
  if (t < nb) {
    int c = hist[t];
    gbase[t] = c ? atomicAdd(&bcursor[t], c) : 0;
    lcur[t] = excl;
  }
  __syncthreads();
  for (int i = t; i < n; i += 512) {
    int d = dst[e0 + i];
    int b = d >> BSHIFT;
    int p = atomicAdd(&lcur[b], 1);
    srec[p] = src[e0 + i] | ((d & BMASK) << 17);
    saddr[p] = gbase[b] + (p - loff[b]);
  }
  __syncthreads();
  for (int i = t; i < n; i += 512) ebuck[saddr[i]] = srec[i];
}

// Exclusive scan over nb bucket counts (single WG).
__global__ __launch_bounds__(1024) void bscan_kernel(const int* __restrict__ bcursor,
                                                     int* __restrict__ bbase, int nb) {
  __shared__ int part[1024];
  const int t = threadIdx.x;
  int c = (t < nb) ? (bcursor[t] - t * BCAP) : 0;
  part[t] = c;
  __syncthreads();
  for (int off = 1; off < 1024; off <<= 1) {
    int v = (t >= off) ? part[t - off] : 0;
    __syncthreads();
    part[t] += v;
    __syncthreads();
  }
  if (t < nb) bbase[t] = part[t] - c;  // exclusive
}

// Phase 2: per-bucket counting sort (256 local-dst keys), scatter DIRECTLY to
// global esrc (writes land in a ~16KB L2-resident window); rowptr + dinv from
// the histogram. LDS = 3KB -> high occupancy.
__global__ __launch_bounds__(1024) void bucketsort_kernel(
    const int* __restrict__ ebuck, const int* __restrict__ bcursor,
    const int* __restrict__ bbase, int* __restrict__ esrc,
    int* __restrict__ rowptr, float* __restrict__ dinv, int N, int E, int nb) {
  __shared__ int hist[256];
  __shared__ int sc[256];
  __shared__ int rowcur[256];
  const int t = threadIdx.x;
  const int bk = blockIdx.x;
  const int base = bk * BCAP;
  const int cnt = bcursor[bk] - base;
  const int gb = bbase[bk];
  if (t < 256) hist[t] = 0;
  __syncthreads();
  for (int i = t; i < cnt; i += 1024)
    atomicAdd(&hist[(ebuck[base + i] >> 17) & BMASK], 1);
  __syncthreads();
  if (t < 256) sc[t] = hist[t];
  __syncthreads();
  for (int off = 1; off < 256; off <<= 1) {
    int v = 0;
    if (t < 256 && t >= off) v = sc[t - off];
    __syncthreads();
    if (t < 256) sc[t] += v;
    __syncthreads();
  }
  if (t < 256) {
    int excl = (t == 0) ? 0 : sc[t - 1];
    rowcur[t] = excl;
    int node = bk * 256 + t;
    if (node < N) {
      rowptr[node] = gb + excl;
      dinv[node] = rsqrtf((float)hist[t] + 1.0f);
    }
  }
  if (bk == nb - 1 && t == 0) rowptr[N] = E;
  __syncthreads();
  for (int i = t; i < cnt; i += 1024) {
    int rec = ebuck[base + i];
    int p = atomicAdd(&rowcur[(rec >> 17) & BMASK], 1);
    esrc[gb + p] = rec & 0x1FFFF;
  }
}

// H[N,64](fp16) = (X[N,K] @ W[K,64]) * dinv[row], via mfma_f32_16x16x32_f16.
template <int K, bool IN_HALF>
__global__ __launch_bounds__(256) void gemm_mfma(const void* __restrict__ Xin,
                                                 const float* __restrict__ W,
                                                 const float* __restrict__ dinv,
                                                 __half* __restrict__ H, int N) {
  __shared__ __align__(16) unsigned char sA[128 * K * 2];
  __shared__ __align__(16) unsigned char sB[64 * K * 2];
  const int t = threadIdx.x;
  const int brow = blockIdx.x * 128;
  constexpr int CH = K / 8;
  for (int idx = t; idx < 128 * CH; idx += 256) {
    int r = idx / CH, c = idx - r * CH;
    int row = brow + r;
    if (row >= N) row = N - 1;
    unsigned int off = (unsigned int)((r * K + c * 8) * 2) ^ ((r & 7) << 4);
    uint4 pk;
    if constexpr (IN_HALF) {
      pk = *reinterpret_cast<const uint4*>((const __half*)Xin + (size_t)row * K + c * 8);
    } else {
      const float4* xp =
          reinterpret_cast<const float4*>((const float*)Xin + (size_t)row * K + c * 8);
      float4 f0 = xp[0], f1 = xp[1];
      pk.x = pack2(f0.x, f0.y);
      pk.y = pack2(f0.z, f0.w);
      pk.z = pack2(f1.x, f1.y);
      pk.w = pack2(f1.z, f1.w);
    }
    *reinterpret_cast<uint4*>(sA + off) = pk;
  }
  for (int idx = t; idx < K * 64; idx += 256) {
    int k = idx >> 6, n = idx & 63;
    __half h = __float2half_rn(W[idx]);
    unsigned int off = (unsigned int)((n * K + k) * 2) ^ ((n & 7) << 4);
    *reinterpret_cast<unsigned short*>(sB + off) =
        *reinterpret_cast<unsigned short*>(&h);
  }
  __syncthreads();

  const int wv = t >> 6, l = t & 63;
  const int lr = l & 15;
  const int lk = (l >> 4) * 8;
  f32x4 acc[2][4] = {};
#pragma unroll
  for (int ks = 0; ks < K / 32; ++ks) {
    f16x8 af[2], bf[4];
#pragma unroll
    for (int m = 0; m < 2; ++m) {
      int r = wv * 32 + m * 16 + lr;
      unsigned int off = (unsigned int)((r * K + ks * 32 + lk) * 2) ^ ((r & 7) << 4);
      af[m] = *reinterpret_cast<const f16x8*>(sA + off);
    }
#pragma unroll
    for (int n = 0; n < 4; ++n) {
      int cc = n * 16 + lr;
      unsigned int off = (unsigned int)((cc * K + ks * 32 + lk) * 2) ^ ((cc & 7) << 4);
      bf[n] = *reinterpret_cast<const f16x8*>(sB + off);
    }
#pragma unroll
    for (int m = 0; m < 2; ++m)
#pragma unroll
      for (int n = 0; n < 4; ++n)
        acc[m][n] = __builtin_amdgcn_mfma_f32_16x16x32_f16(af[m], bf[n], acc[m][n],
                                                           0, 0, 0);
  }
#pragma unroll
  for (int m = 0; m < 2; ++m) {
#pragma unroll
    for (int j = 0; j < 4; ++j) {
      int row = brow + wv * 32 + m * 16 + (l >> 4) * 4 + j;
      if (row < N) {
        float di = dinv[row];
#pragma unroll
        for (int n = 0; n < 4; ++n) {
          float v = acc[m][n][j] * di;
          H[(size_t)row * 64 + n * 16 + lr] = __float2half_rn(v);
        }
      }
    }
  }
}

// 4 nodes per wave: nid=lane>>4 (node), g=(lane>>3)&1 (edge group),
// cl=lane&7 (16B slice of 128B row). Per iteration: 4 wave-level uint4
// gathers (8 edges each, 2 per node), 4 independent streams.
template <bool RELU, bool OUT_HALF>
__global__ __launch_bounds__(256) void agg_kernel(const __half* __restrict__ hs,
                                                  const int* __restrict__ rowptr,
                                                  const int* __restrict__ esrc,
                                                  const float* __restrict__ dinv,
                                                  const float* __restrict__ b,
                                                  void* __restrict__ outv, int N) {
  const int wv = threadIdx.x >> 6;
  const int lane = threadIdx.x & 63;
  const int nid = lane >> 4;
  const int g = (lane >> 3) & 1;
  const int cl = lane & 7;
  const int node = blockIdx.x * 16 + wv * 4 + nid;
  const unsigned int choff = (unsigned int)cl << 4;
  const unsigned char* __restrict__ hb = (const unsigned char*)hs;
  int beg = 0, end = 0;
  if (node < N) {
    beg = rowptr[node];
    end = rowptr[node + 1];
  }
  __half2 accA[4] = {{0.f, 0.f}, {0.f, 0.f}, {0.f, 0.f}, {0.f, 0.f}};
  __half2 accB[4] = {{0.f, 0.f}, {0.f, 0.f}, {0.f, 0.f}, {0.f, 0.f}};
  int k = beg + g;
  while (k < end) {
    int s0 = esrc[min(k,     end - 1)];
    int s1 = esrc[min(k + 2, end - 1)];
    int s2 = esrc[min(k + 4, end - 1)];
    int s3 = esrc[min(k + 6, end - 1)];
    uint4 v0 = *reinterpret_cast<const uint4*>(hb + (((unsigned int)s0 << 7) + choff));
    uint4 v1 = *reinterpret_cast<const uint4*>(hb + (((unsigned int)s1 << 7) + choff));
    uint4 v2 = *reinterpret_cast<const uint4*>(hb + (((unsigned int)s2 << 7) + choff));
    uint4 v3 = *reinterpret_cast<const uint4*>(hb + (((unsigned int)s3 << 7) + choff));
    {
      accA[0] = h2add(accA[0], bcast_h2(v0.x));
      accA[1] = h2add(accA[1], bcast_h2(v0.y));
      accA[2] = h2add(accA[2], bcast_h2(v0.z));
      accA[3] = h2add(accA[3], bcast_h2(v0.w));
    }
    if (k + 2 < end) {
      accB[0] = h2add(accB[0], bcast_h2(v1.x));
      accB[1] = h2add(accB[1], bcast_h2(v1.y));
      accB[2] = h2add(accB[2], bcast_h2(v1.z));
      accB[3] = h2add(accB[3], bcast_h2(v1.w));
    }
    if (k + 4 < end) {
      accA[0] = h2add(accA[0], bcast_h2(v2.x));
      accA[1] = h2add(accA[1], bcast_h2(v2.y));
      accA[2] = h2add(accA[2], bcast_h2(v2.z));
      accA[3] = h2add(accA[3], bcast_h2(v2.w));
    }
    if (k + 6 < end) {
      accB[0] = h2add(accB[0], bcast_h2(v3.x));
      accB[1] = h2add(accB[1], bcast_h2(v3.y));
      accB[2] = h2add(accB[2], bcast_h2(v3.z));
      accB[3] = h2add(accB[3], bcast_h2(v3.w));
    }
    k += 8;
  }
#pragma unroll
  for (int r = 0; r < 4; ++r) accA[r] = h2add(accA[r], accB[r]);
#pragma unroll
  for (int r = 0; r < 4; ++r) {
    int u = __shfl_xor(*reinterpret_cast<int*>(&accA[r]), 8);
    accA[r] = h2add(accA[r], *reinterpret_cast<__half2*>(&u));
  }
  if (g == 0 && node < N) {
    uint4 sv = *reinterpret_cast<const uint4*>(hb + (((unsigned int)node << 7) + choff));
    float di = dinv[node];
    const float4* bv = reinterpret_cast<const float4*>(b);
    float4 b0 = bv[cl * 2], b1 = bv[cl * 2 + 1];
    float r[8];
#pragma unroll
    for (int q = 0; q < 4; ++q) {
      float2 av = __half22float2(accA[q]);
      float2 sf = __half22float2(bcast_h2((&sv.x)[q]));
      r[2 * q]     = (av.x + sf.x) * di;
      r[2 * q + 1] = (av.y + sf.y) * di;
    }
    r[0] += b0.x; r[1] += b0.y; r[2] += b0.z; r[3] += b0.w;
    r[4] += b1.x; r[5] += b1.y; r[6] += b1.z; r[7] += b1.w;
    if (RELU) {
#pragma unroll
      for (int q = 0; q < 8; ++q) r[q] = fmaxf(r[q], 0.f);
    }
    if constexpr (OUT_HALF) {
      uint4 pk;
      pk.x = pack2(r[0], r[1]);
      pk.y = pack2(r[2], r[3]);
      pk.z = pack2(r[4], r[5]);
      pk.w = pack2(r[6], r[7]);
      reinterpret_cast<uint4*>(outv)[(size_t)node * 8 + cl] = pk;
    } else {
      float4* ov = reinterpret_cast<float4*>(outv);
      ov[(size_t)node * 16 + cl * 2]     = make_float4(r[0], r[1], r[2], r[3]);
      ov[(size_t)node * 16 + cl * 2 + 1] = make_float4(r[4], r[5], r[6], r[7]);
    }
  }
}

extern "C" void kernel_launch(void* const* d_in, const int* in_sizes, int n_in,
                              void* d_out, int out_size, void* d_ws, size_t ws_size,
                              hipStream_t stream) {
  const float* x  = (const float*)d_in[0];
  const int*   ei = (const int*)d_in[1];
  const float* W1 = (const float*)d_in[2];
  const float* b1 = (const float*)d_in[3];
  const float* W2 = (const float*)d_in[4];
  const float* b2 = (const float*)d_in[5];
  const int N = in_sizes[0] / 128;
  const int E = in_sizes[1] / 2;
  const int* src = ei;
  const int* dst = ei + E;
  const int nb = (N + 255) >> BSHIFT;  // 391 buckets of 256 nodes

  char* ws = (char*)d_ws;
  int*    bcursor = (int*)ws;                       // nb ints
  int*    bbase   = (int*)(ws + (1 << 19));         // nb ints   @ 512KB
  float*  dinv    = (float*)(ws + (1 << 20));       // N floats  @ 1MB
  int*    rowptr  = (int*)(ws + 3 * (1 << 19));     // N+1 ints  @ 1.5MB
  int*    esrc    = (int*)(ws + (1 << 21));         // E ints    @ 2MB   (6.4MB)
  int*    ebuck   = (int*)(ws + 9 * (1 << 20));     // nb*BCAP   @ 9MB   (12.8MB)
  __half* hs      = (__half*)(ws + 22 * (1 << 20)); // N*64 fp16 @ 22MB  (12.8MB)
  __half* y1h     = (__half*)(ws + 36 * (1 << 20)); // N*64 fp16 @ 36MB  (12.8MB)
  float*  out = (float*)d_out;

  // CSR build (shared by both layers)
  initcur_kernel<<<(nb + 255) / 256, 256, 0, stream>>>(bcursor, nb);
  chunksort_kernel<<<(E + CHUNK - 1) / CHUNK, 512, 0, stream>>>(src, dst, bcursor,
                                                                ebuck, E, nb);
  bscan_kernel<<<1, 1024, 0, stream>>>(bcursor, bbase, nb);
  bucketsort_kernel<<<nb, 1024, 0, stream>>>(ebuck, bcursor, bbase, esrc, rowptr,
                                             dinv, N, E, nb);

  const int gemmGrid = (N + 127) / 128;
  const int aggGrid = (N + 15) / 16;
  // layer 1: hs1(fp16) -> hs ; y1(fp16, relu) -> y1h
  gemm_mfma<128, false><<<gemmGrid, 256, 0, stream>>>(x, W1, dinv, hs, N);
  agg_kernel<true, true><<<aggGrid, 256, 0, stream>>>(hs, rowptr, esrc, dinv, b1,
                                                      y1h, N);
  // layer 2: hs2(fp16) -> hs (reuse) ; y2(fp32) -> out
  gemm_mfma<64, true><<<gemmGrid, 256, 0, stream>>>(y1h, W2, dinv, hs, N);
  agg_kernel<false, false><<<aggGrid, 256, 0, stream>>>(hs, rowptr, esrc, dinv, b2,
                                                        out, N);
}

// Round 13
// 135.015 us; speedup vs baseline: 1.2966x; 1.0678x over previous
//
#include <hip/hip_runtime.h>
#include <hip/hip_fp16.h>

// GCN 2-layer forward. CSR via two-phase dst-sort, MFMA fp16 GEMMs,
// fp16 message tables, 4-node-per-wave gather aggregation.
// R13: gemm2 fused into agg1 (block computes y1 tile -> LDS -> 8 MFMAs ->
// hs2 directly; y1h buffer and gemm_mfma<64> dispatch eliminated).

#define CHUNK 2048
#define BCAP  8192
#define NB_PAD 512
#define BSHIFT 8
#define BMASK 255

typedef _Float16 f16x8 __attribute__((ext_vector_type(8)));
typedef float f32x4 __attribute__((ext_vector_type(4)));

__device__ __forceinline__ unsigned int pack2(float a, float b) {
  __half2 h = __floats2half2_rn(a, b);
  return *reinterpret_cast<unsigned int*>(&h);
}
__device__ __forceinline__ __half2 h2add(__half2 a, __half2 b) {
  return __hadd2(a, b);
}
__device__ __forceinline__ __half2 bcast_h2(unsigned int u) {
  return *reinterpret_cast<__half2*>(&u);
}

__global__ __launch_bounds__(256) void initcur_kernel(int* __restrict__ bcursor,
                                                      int nb) {
  int i = blockIdx.x * 256 + threadIdx.x;
  if (i < nb) bcursor[i] = i * BCAP;
}

// Phase 1: group edges by bucket b = dst>>8 into bucket-major ebuck.
__global__ __launch_bounds__(512) void chunksort_kernel(
    const int* __restrict__ src, const int* __restrict__ dst,
    int* __restrict__ bcursor, int* __restrict__ ebuck, int nE, int nb) {
  __shared__ int hist[NB_PAD];
  __shared__ int loff[NB_PAD];
  __shared__ int gbase[NB_PAD];
  __shared__ int lcur[NB_PAD];
  __shared__ int part[NB_PAD];
  __shared__ int srec[CHUNK];
  __shared__ int saddr[CHUNK];
  const int t = threadIdx.x;
  const int e0 = blockIdx.x * CHUNK;
  const int n = min(CHUNK, nE - e0);
  hist[t] = 0;
  __syncthreads();
  for (int i = t; i < n; i += 512) atomicAdd(&hist[dst[e0 + i] >> BSHIFT], 1);
  __syncthreads();
  part[t] = hist[t];
  __syncthreads();
  for (int off = 1; off < NB_PAD; off <<= 1) {
    int v = (t >= off) ? part[t - off] : 0;
    __syncthreads();
    part[t] += v;
    __syncthreads();
  }
  int excl = (t == 0) ? 0 : part[t - 1];
  loff[t] = excl;
  if (t < nb) {
    int c = hist[t];
    gbase[t] = c ? atomicAdd(&bcursor[t], c) : 0;
    lcur[t] = excl;
  }
  __syncthreads();
  for (int i = t; i < n; i += 512) {
    int d = dst[e0 + i];
    int b = d >> BSHIFT;
    int p = atomicAdd(&lcur[b], 1);
    srec[p] = src[e0 + i] | ((d & BMASK) << 17);
    saddr[p] = gbase[b] + (p - loff[b]);
  }
  __syncthreads();
  for (int i = t; i < n; i += 512) ebuck[saddr[i]] = srec[i];
}

__global__ __launch_bounds__(1024) void bscan_kernel(const int* __restrict__ bcursor,
                                                     int* __restrict__ bbase, int nb) {
  __shared__ int part[1024];
  const int t = threadIdx.x;
  int c = (t < nb) ? (bcursor[t] - t * BCAP) : 0;
  part[t] = c;
  __syncthreads();
  for (int off = 1; off < 1024; off <<= 1) {
    int v = (t >= off) ? part[t - off] : 0;
    __syncthreads();
    part[t] += v;
    __syncthreads();
  }
  if (t < nb) bbase[t] = part[t] - c;  // exclusive
}

// Phase 2: per-bucket counting sort (256 keys), direct-global scatter.
__global__ __launch_bounds__(1024) void bucketsort_kernel(
    const int* __restrict__ ebuck, const int* __restrict__ bcursor,
    const int* __restrict__ bbase, int* __restrict__ esrc,
    int* __restrict__ rowptr, float* __restrict__ dinv, int N, int E, int nb) {
  __shared__ int hist[256];
  __shared__ int sc[256];
  __shared__ int rowcur[256];
  const int t = threadIdx.x;
  const int bk = blockIdx.x;
  const int base = bk * BCAP;
  const int cnt = bcursor[bk] - base;
  const int gb = bbase[bk];
  if (t < 256) hist[t] = 0;
  __syncthreads();
  for (int i = t; i < cnt; i += 1024)
    atomicAdd(&hist[(ebuck[base + i] >> 17) & BMASK], 1);
  __syncthreads();
  if (t < 256) sc[t] = hist[t];
  __syncthreads();
  for (int off = 1; off < 256; off <<= 1) {
    int v = 0;
    if (t < 256 && t >= off) v = sc[t - off];
    __syncthreads();
    if (t < 256) sc[t] += v;
    __syncthreads();
  }
  if (t < 256) {
    int excl = (t == 0) ? 0 : sc[t - 1];
    rowcur[t] = excl;
    int node = bk * 256 + t;
    if (node < N) {
      rowptr[node] = gb + excl;
      dinv[node] = rsqrtf((float)hist[t] + 1.0f);
    }
  }
  if (bk == nb - 1 && t == 0) rowptr[N] = E;
  __syncthreads();
  for (int i = t; i < cnt; i += 1024) {
    int rec = ebuck[base + i];
    int p = atomicAdd(&rowcur[(rec >> 17) & BMASK], 1);
    esrc[gb + p] = rec & 0x1FFFF;
  }
}

// H[N,64](fp16) = (X[N,K] @ W[K,64]) * dinv[row], via mfma_f32_16x16x32_f16.
template <int K, bool IN_HALF>
__global__ __launch_bounds__(256) void gemm_mfma(const void* __restrict__ Xin,
                                                 const float* __restrict__ W,
                                                 const float* __restrict__ dinv,
                                                 __half* __restrict__ H, int N) {
  __shared__ __align__(16) unsigned char sA[128 * K * 2];
  __shared__ __align__(16) unsigned char sB[64 * K * 2];
  const int t = threadIdx.x;
  const int brow = blockIdx.x * 128;
  constexpr int CH = K / 8;
  for (int idx = t; idx < 128 * CH; idx += 256) {
    int r = idx / CH, c = idx - r * CH;
    int row = brow + r;
    if (row >= N) row = N - 1;
    unsigned int off = (unsigned int)((r * K + c * 8) * 2) ^ ((r & 7) << 4);
    uint4 pk;
    if constexpr (IN_HALF) {
      pk = *reinterpret_cast<const uint4*>((const __half*)Xin + (size_t)row * K + c * 8);
    } else {
      const float4* xp =
          reinterpret_cast<const float4*>((const float*)Xin + (size_t)row * K + c * 8);
      float4 f0 = xp[0], f1 = xp[1];
      pk.x = pack2(f0.x, f0.y);
      pk.y = pack2(f0.z, f0.w);
      pk.z = pack2(f1.x, f1.y);
      pk.w = pack2(f1.z, f1.w);
    }
    *reinterpret_cast<uint4*>(sA + off) = pk;
  }
  for (int idx = t; idx < K * 64; idx += 256) {
    int k = idx >> 6, n = idx & 63;
    __half h = __float2half_rn(W[idx]);
    unsigned int off = (unsigned int)((n * K + k) * 2) ^ ((n & 7) << 4);
    *reinterpret_cast<unsigned short*>(sB + off) =
        *reinterpret_cast<unsigned short*>(&h);
  }
  __syncthreads();

  const int wv = t >> 6, l = t & 63;
  const int lr = l & 15;
  const int lk = (l >> 4) * 8;
  f32x4 acc[2][4] = {};
#pragma unroll
  for (int ks = 0; ks < K / 32; ++ks) {
    f16x8 af[2], bf[4];
#pragma unroll
    for (int m = 0; m < 2; ++m) {
      int r = wv * 32 + m * 16 + lr;
      unsigned int off = (unsigned int)((r * K + ks * 32 + lk) * 2) ^ ((r & 7) << 4);
      af[m] = *reinterpret_cast<const f16x8*>(sA + off);
    }
#pragma unroll
    for (int n = 0; n < 4; ++n) {
      int cc = n * 16 + lr;
      unsigned int off = (unsigned int)((cc * K + ks * 32 + lk) * 2) ^ ((cc & 7) << 4);
      bf[n] = *reinterpret_cast<const f16x8*>(sB + off);
    }
#pragma unroll
    for (int m = 0; m < 2; ++m)
#pragma unroll
      for (int n = 0; n < 4; ++n)
        acc[m][n] = __builtin_amdgcn_mfma_f32_16x16x32_f16(af[m], bf[n], acc[m][n],
                                                           0, 0, 0);
  }
#pragma unroll
  for (int m = 0; m < 2; ++m) {
#pragma unroll
    for (int j = 0; j < 4; ++j) {
      int row = brow + wv * 32 + m * 16 + (l >> 4) * 4 + j;
      if (row < N) {
        float di = dinv[row];
#pragma unroll
        for (int n = 0; n < 4; ++n) {
          float v = acc[m][n][j] * di;
          H[(size_t)row * 64 + n * 16 + lr] = __float2half_rn(v);
        }
      }
    }
  }
}

// Fused agg1 + gemm2: per block (16 nodes), aggregate y1 = relu(GCN1) into
// a 16x64 fp16 LDS tile, then wave 0 computes hs2 = (y1 @ W2) * dinv via
// 8 MFMAs (W2^T staged fp16 in LDS) and stores hs2 directly.
__global__ __launch_bounds__(256) void agg_gemm_kernel(
    const __half* __restrict__ hs, const int* __restrict__ rowptr,
    const int* __restrict__ esrc, const float* __restrict__ dinv,
    const float* __restrict__ b, const float* __restrict__ W2,
    __half* __restrict__ H2, int N) {
  __shared__ __align__(16) unsigned char sY[16 * 64 * 2];   // y1 tile (swizzled)
  __shared__ __align__(16) unsigned char sW[64 * 64 * 2];   // W2^T (swizzled)
  const int t = threadIdx.x;
  // stage W2^T fp16 (W2 is [k][n] row-major)
  for (int idx = t; idx < 64 * 64; idx += 256) {
    int k = idx >> 6, n = idx & 63;
    __half h = __float2half_rn(W2[idx]);
    unsigned int off = (unsigned int)((n * 64 + k) * 2) ^ ((n & 7) << 4);
    *reinterpret_cast<unsigned short*>(sW + off) =
        *reinterpret_cast<unsigned short*>(&h);
  }

  const int wv = t >> 6;
  const int lane = t & 63;
  const int nid = lane >> 4;
  const int g = (lane >> 3) & 1;
  const int cl = lane & 7;
  const int nodeL = wv * 4 + nid;                 // node index within block
  const int node = blockIdx.x * 16 + nodeL;
  const unsigned int choff = (unsigned int)cl << 4;
  const unsigned char* __restrict__ hb = (const unsigned char*)hs;
  int beg = 0, end = 0;
  if (node < N) {
    beg = rowptr[node];
    end = rowptr[node + 1];
  }
  __half2 accA[4] = {{0.f, 0.f}, {0.f, 0.f}, {0.f, 0.f}, {0.f, 0.f}};
  __half2 accB[4] = {{0.f, 0.f}, {0.f, 0.f}, {0.f, 0.f}, {0.f, 0.f}};
  int k = beg + g;
  while (k < end) {
    int s0 = esrc[min(k,     end - 1)];
    int s1 = esrc[min(k + 2, end - 1)];
    int s2 = esrc[min(k + 4, end - 1)];
    int s3 = esrc[min(k + 6, end - 1)];
    uint4 v0 = *reinterpret_cast<const uint4*>(hb + (((unsigned int)s0 << 7) + choff));
    uint4 v1 = *reinterpret_cast<const uint4*>(hb + (((unsigned int)s1 << 7) + choff));
    uint4 v2 = *reinterpret_cast<const uint4*>(hb + (((unsigned int)s2 << 7) + choff));
    uint4 v3 = *reinterpret_cast<const uint4*>(hb + (((unsigned int)s3 << 7) + choff));
    {
      accA[0] = h2add(accA[0], bcast_h2(v0.x));
      accA[1] = h2add(accA[1], bcast_h2(v0.y));
      accA[2] = h2add(accA[2], bcast_h2(v0.z));
      accA[3] = h2add(accA[3], bcast_h2(v0.w));
    }
    if (k + 2 < end) {
      accB[0] = h2add(accB[0], bcast_h2(v1.x));
      accB[1] = h2add(accB[1], bcast_h2(v1.y));
      accB[2] = h2add(accB[2], bcast_h2(v1.z));
      accB[3] = h2add(accB[3], bcast_h2(v1.w));
    }
    if (k + 4 < end) {
      accA[0] = h2add(accA[0], bcast_h2(v2.x));
      accA[1] = h2add(accA[1], bcast_h2(v2.y));
      accA[2] = h2add(accA[2], bcast_h2(v2.z));
      accA[3] = h2add(accA[3], bcast_h2(v2.w));
    }
    if (k + 6 < end) {
      accB[0] = h2add(accB[0], bcast_h2(v3.x));
      accB[1] = h2add(accB[1], bcast_h2(v3.y));
      accB[2] = h2add(accB[2], bcast_h2(v3.z));
      accB[3] = h2add(accB[3], bcast_h2(v3.w));
    }
    k += 8;
  }
#pragma unroll
  for (int r = 0; r < 4; ++r) accA[r] = h2add(accA[r], accB[r]);
#pragma unroll
  for (int r = 0; r < 4; ++r) {
    int u = __shfl_xor(*reinterpret_cast<int*>(&accA[r]), 8);
    accA[r] = h2add(accA[r], *reinterpret_cast<__half2*>(&u));
  }
  if (g == 0 && node < N) {
    uint4 sv = *reinterpret_cast<const uint4*>(hb + (((unsigned int)node << 7) + choff));
    float di = dinv[node];
    const float4* bv = reinterpret_cast<const float4*>(b);
    float4 b0 = bv[cl * 2], b1 = bv[cl * 2 + 1];
    float r[8];
#pragma unroll
    for (int q = 0; q < 4; ++q) {
      float2 av = __half22float2(accA[q]);
      float2 sf = __half22float2(bcast_h2((&sv.x)[q]));
      r[2 * q]     = (av.x + sf.x) * di;
      r[2 * q + 1] = (av.y + sf.y) * di;
    }
    r[0] += b0.x; r[1] += b0.y; r[2] += b0.z; r[3] += b0.w;
    r[4] += b1.x; r[5] += b1.y; r[6] += b1.z; r[7] += b1.w;
#pragma unroll
    for (int q = 0; q < 8; ++q) r[q] = fmaxf(r[q], 0.f);   // relu (layer 1)
    uint4 pk;
    pk.x = pack2(r[0], r[1]);
    pk.y = pack2(r[2], r[3]);
    pk.z = pack2(r[4], r[5]);
    pk.w = pack2(r[6], r[7]);
    unsigned int off = (unsigned int)((nodeL * 64 + cl * 8) * 2) ^ ((nodeL & 7) << 4);
    *reinterpret_cast<uint4*>(sY + off) = pk;
  }
  __syncthreads();
  // wave 0: hs2[16,64] = (y1[16,64] @ W2[64,64]) * dinv
  if (wv == 0) {
    const int lr = lane & 15;
    const int lk = (lane >> 4) * 8;
    f32x4 acc[4] = {};
#pragma unroll
    for (int ks = 0; ks < 2; ++ks) {
      unsigned int aoff = (unsigned int)((lr * 64 + ks * 32 + lk) * 2) ^ ((lr & 7) << 4);
      f16x8 af = *reinterpret_cast<const f16x8*>(sY + aoff);
#pragma unroll
      for (int n = 0; n < 4; ++n) {
        int cc = n * 16 + lr;
        unsigned int boff = (unsigned int)((cc * 64 + ks * 32 + lk) * 2) ^ ((cc & 7) << 4);
        f16x8 bf = *reinterpret_cast<const f16x8*>(sW + boff);
        acc[n] = __builtin_amdgcn_mfma_f32_16x16x32_f16(af, bf, acc[n], 0, 0, 0);
      }
    }
#pragma unroll
    for (int j = 0; j < 4; ++j) {
      int rowL = (lane >> 4) * 4 + j;
      int row = blockIdx.x * 16 + rowL;
      if (row < N) {
        float di = dinv[row];
#pragma unroll
        for (int n = 0; n < 4; ++n) {
          float v = acc[n][j] * di;
          H2[(size_t)row * 64 + n * 16 + lr] = __float2half_rn(v);
        }
      }
    }
  }
}

// Final aggregation (layer 2): out fp32.
__global__ __launch_bounds__(256) void agg_kernel(const __half* __restrict__ hs,
                                                  const int* __restrict__ rowptr,
                                                  const int* __restrict__ esrc,
                                                  const float* __restrict__ dinv,
                                                  const float* __restrict__ b,
                                                  float* __restrict__ outv, int N) {
  const int wv = threadIdx.x >> 6;
  const int lane = threadIdx.x & 63;
  const int nid = lane >> 4;
  const int g = (lane >> 3) & 1;
  const int cl = lane & 7;
  const int node = blockIdx.x * 16 + wv * 4 + nid;
  const unsigned int choff = (unsigned int)cl << 4;
  const unsigned char* __restrict__ hb = (const unsigned char*)hs;
  int beg = 0, end = 0;
  if (node < N) {
    beg = rowptr[node];
    end = rowptr[node + 1];
  }
  __half2 accA[4] = {{0.f, 0.f}, {0.f, 0.f}, {0.f, 0.f}, {0.f, 0.f}};
  __half2 accB[4] = {{0.f, 0.f}, {0.f, 0.f}, {0.f, 0.f}, {0.f, 0.f}};
  int k = beg + g;
  while (k < end) {
    int s0 = esrc[min(k,     end - 1)];
    int s1 = esrc[min(k + 2, end - 1)];
    int s2 = esrc[min(k + 4, end - 1)];
    int s3 = esrc[min(k + 6, end - 1)];
    uint4 v0 = *reinterpret_cast<const uint4*>(hb + (((unsigned int)s0 << 7) + choff));
    uint4 v1 = *reinterpret_cast<const uint4*>(hb + (((unsigned int)s1 << 7) + choff));
    uint4 v2 = *reinterpret_cast<const uint4*>(hb + (((unsigned int)s2 << 7) + choff));
    uint4 v3 = *reinterpret_cast<const uint4*>(hb + (((unsigned int)s3 << 7) + choff));
    {
      accA[0] = h2add(accA[0], bcast_h2(v0.x));
      accA[1] = h2add(accA[1], bcast_h2(v0.y));
      accA[2] = h2add(accA[2], bcast_h2(v0.z));
      accA[3] = h2add(accA[3], bcast_h2(v0.w));
    }
    if (k + 2 < end) {
      accB[0] = h2add(accB[0], bcast_h2(v1.x));
      accB[1] = h2add(accB[1], bcast_h2(v1.y));
      accB[2] = h2add(accB[2], bcast_h2(v1.z));
      accB[3] = h2add(accB[3], bcast_h2(v1.w));
    }
    if (k + 4 < end) {
      accA[0] = h2add(accA[0], bcast_h2(v2.x));
      accA[1] = h2add(accA[1], bcast_h2(v2.y));
      accA[2] = h2add(accA[2], bcast_h2(v2.z));
      accA[3] = h2add(accA[3], bcast_h2(v2.w));
    }
    if (k + 6 < end) {
      accB[0] = h2add(accB[0], bcast_h2(v3.x));
      accB[1] = h2add(accB[1], bcast_h2(v3.y));
      accB[2] = h2add(accB[2], bcast_h2(v3.z));
      accB[3] = h2add(accB[3], bcast_h2(v3.w));
    }
    k += 8;
  }
#pragma unroll
  for (int r = 0; r < 4; ++r) accA[r] = h2add(accA[r], accB[r]);
#pragma unroll
  for (int r = 0; r < 4; ++r) {
    int u = __shfl_xor(*reinterpret_cast<int*>(&accA[r]), 8);
    accA[r] = h2add(accA[r], *reinterpret_cast<__half2*>(&u));
  }
  if (g == 0 && node < N) {
    uint4 sv = *reinterpret_cast<const uint4*>(hb + (((unsigned int)node << 7) + choff));
    float di = dinv[node];
    const float4* bv = reinterpret_cast<const float4*>(b);
    float4 b0 = bv[cl * 2], b1 = bv[cl * 2 + 1];
    float r[8];
#pragma unroll
    for (int q = 0; q < 4; ++q) {
      float2 av = __half22float2(accA[q]);
      float2 sf = __half22float2(bcast_h2((&sv.x)[q]));
      r[2 * q]     = (av.x + sf.x) * di;
      r[2 * q + 1] = (av.y + sf.y) * di;
    }
    r[0] += b0.x; r[1] += b0.y; r[2] += b0.z; r[3] += b0.w;
    r[4] += b1.x; r[5] += b1.y; r[6] += b1.z; r[7] += b1.w;
    float4* ov = reinterpret_cast<float4*>(outv);
    ov[(size_t)node * 16 + cl * 2]     = make_float4(r[0], r[1], r[2], r[3]);
    ov[(size_t)node * 16 + cl * 2 + 1] = make_float4(r[4], r[5], r[6], r[7]);
  }
}

extern "C" void kernel_launch(void* const* d_in, const int* in_sizes, int n_in,
                              void* d_out, int out_size, void* d_ws, size_t ws_size,
                              hipStream_t stream) {
  const float* x  = (const float*)d_in[0];
  const int*   ei = (const int*)d_in[1];
  const float* W1 = (const float*)d_in[2];
  const float* b1 = (const float*)d_in[3];
  const float* W2 = (const float*)d_in[4];
  const float* b2 = (const float*)d_in[5];
  const int N = in_sizes[0] / 128;
  const int E = in_sizes[1] / 2;
  const int* src = ei;
  const int* dst = ei + E;
  const int nb = (N + 255) >> BSHIFT;  // 391 buckets of 256 nodes

  char* ws = (char*)d_ws;
  int*    bcursor = (int*)ws;                       // nb ints
  int*    bbase   = (int*)(ws + (1 << 19));         // nb ints   @ 512KB
  float*  dinv    = (float*)(ws + (1 << 20));       // N floats  @ 1MB
  int*    rowptr  = (int*)(ws + 3 * (1 << 19));     // N+1 ints  @ 1.5MB
  int*    esrc    = (int*)(ws + (1 << 21));         // E ints    @ 2MB   (6.4MB)
  int*    ebuck   = (int*)(ws + 9 * (1 << 20));     // nb*BCAP   @ 9MB   (12.8MB)
  __half* hs      = (__half*)(ws + 22 * (1 << 20)); // N*64 fp16 @ 22MB  (12.8MB)
  __half* hs2     = (__half*)(ws + 36 * (1 << 20)); // N*64 fp16 @ 36MB  (12.8MB)
  float*  out = (float*)d_out;

  // CSR build (shared by both layers)
  initcur_kernel<<<(nb + 255) / 256, 256, 0, stream>>>(bcursor, nb);
  chunksort_kernel<<<(E + CHUNK - 1) / CHUNK, 512, 0, stream>>>(src, dst, bcursor,
                                                                ebuck, E, nb);
  bscan_kernel<<<1, 1024, 0, stream>>>(bcursor, bbase, nb);
  bucketsort_kernel<<<nb, 1024, 0, stream>>>(ebuck, bcursor, bbase, esrc, rowptr,
                                             dinv, N, E, nb);

  const int gemmGrid = (N + 127) / 128;
  const int aggGrid = (N + 15) / 16;
  // layer 1 GEMM: hs1(fp16) -> hs
  gemm_mfma<128, false><<<gemmGrid, 256, 0, stream>>>(x, W1, dinv, hs, N);
  // fused layer-1 aggregation + layer-2 GEMM: hs2(fp16) directly
  agg_gemm_kernel<<<aggGrid, 256, 0, stream>>>(hs, rowptr, esrc, dinv, b1, W2,
                                               hs2, N);
  // layer-2 aggregation: out fp32
  agg_kernel<<<aggGrid, 256, 0, stream>>>(hs2, rowptr, esrc, dinv, b2, out, N);
}

// Round 14
// 130.848 us; speedup vs baseline: 1.3379x; 1.0318x over previous
//
#include <hip/hip_runtime.h>
#include <hip/hip_fp16.h>

// GCN 2-layer forward. CSR via two-phase dst-sort, MFMA fp16 GEMMs,
// fp16 message tables, 4-node-per-wave gather aggregation, gemm2 fused
// into agg1. R14: bscan folded into bucketsort (per-block reduction),
// shfl-based scans (18->2 barriers), 6 dispatches.

#define CHUNK 2048
#define BCAP  8192
#define NB_PAD 512
#define BSHIFT 8
#define BMASK 255

typedef _Float16 f16x8 __attribute__((ext_vector_type(8)));
typedef float f32x4 __attribute__((ext_vector_type(4)));

__device__ __forceinline__ unsigned int pack2(float a, float b) {
  __half2 h = __floats2half2_rn(a, b);
  return *reinterpret_cast<unsigned int*>(&h);
}
__device__ __forceinline__ __half2 h2add(__half2 a, __half2 b) {
  return __hadd2(a, b);
}
__device__ __forceinline__ __half2 bcast_h2(unsigned int u) {
  return *reinterpret_cast<__half2*>(&u);
}

__global__ __launch_bounds__(256) void initcur_kernel(int* __restrict__ bcursor,
                                                      int nb) {
  int i = blockIdx.x * 256 + threadIdx.x;
  if (i < nb) bcursor[i] = i * BCAP;
}

// Phase 1: group edges by bucket b = dst>>8 into bucket-major ebuck.
// Scan via wave shfl (2 barriers instead of 18).
__global__ __launch_bounds__(512) void chunksort_kernel(
    const int* __restrict__ src, const int* __restrict__ dst,
    int* __restrict__ bcursor, int* __restrict__ ebuck, int nE, int nb) {
  __shared__ int hist[NB_PAD];
  __shared__ int loff[NB_PAD];
  __shared__ int gbase[NB_PAD];
  __shared__ int lcur[NB_PAD];
  __shared__ int wsum[8];
  __shared__ int srec[CHUNK];
  __shared__ int saddr[CHUNK];
  const int t = threadIdx.x;
  const int lane = t & 63, w = t >> 6;
  const int e0 = blockIdx.x * CHUNK;
  const int n = min(CHUNK, nE - e0);
  hist[t] = 0;
  __syncthreads();
  for (int i = t; i < n; i += 512) atomicAdd(&hist[dst[e0 + i] >> BSHIFT], 1);
  __syncthreads();
  // exclusive scan of hist over 512 threads: wave shfl + 8 wave sums
  int h = hist[t];
  int x = h;
#pragma unroll
  for (int off = 1; off < 64; off <<= 1) {
    int v = __shfl_up(x, off);
    if (lane >= off) x += v;
  }
  if (lane == 63) wsum[w] = x;
  __syncthreads();
  if (w == 0 && lane < 8) {
    int s = wsum[lane];
#pragma unroll
    for (int off = 1; off < 8; off <<= 1) {
      int v = __shfl_up(s, off);
      if (lane >= off) s += v;
    }
    wsum[lane] = s;  // inclusive wave sums
  }
  __syncthreads();
  int excl = ((w == 0) ? 0 : wsum[w - 1]) + x - h;
  loff[t] = excl;
  lcur[t] = excl;
  if (t < nb) gbase[t] = h ? atomicAdd(&bcursor[t], h) : 0;
  __syncthreads();
  for (int i = t; i < n; i += 512) {
    int d = dst[e0 + i];
    int b = d >> BSHIFT;
    int p = atomicAdd(&lcur[b], 1);
    srec[p] = src[e0 + i] | ((d & BMASK) << 17);
    saddr[p] = gbase[b] + (p - loff[b]);
  }
  __syncthreads();
  for (int i = t; i < n; i += 512) ebuck[saddr[i]] = srec[i];
}

// Phase 2: per-bucket counting sort (256 keys), direct-global scatter.
// bbase computed in-kernel as a reduction over bcursor[0..bk).
__global__ __launch_bounds__(1024) void bucketsort_kernel(
    const int* __restrict__ ebuck, const int* __restrict__ bcursor,
    int* __restrict__ esrc, int* __restrict__ rowptr,
    float* __restrict__ dinv, int N, int E, int nb) {
  __shared__ int hist[256];
  __shared__ int rowcur[256];
  __shared__ int red[1024];
  __shared__ int wsum[4];
  __shared__ int gbs;
  const int t = threadIdx.x;
  const int bk = blockIdx.x;
  const int base = bk * BCAP;
  const int cnt = bcursor[bk] - base;
  // bbase reduction: sum of counts of buckets < bk
  int partial = 0;
  for (int j = t; j < bk; j += 1024) partial += bcursor[j] - j * BCAP;
  red[t] = partial;
  if (t < 256) hist[t] = 0;
  __syncthreads();
  for (int off = 512; off > 0; off >>= 1) {
    if (t < off) red[t] += red[t + off];
    __syncthreads();
  }
  if (t == 0) gbs = red[0];
  for (int i = t; i < cnt; i += 1024)
    atomicAdd(&hist[(ebuck[base + i] >> 17) & BMASK], 1);
  __syncthreads();
  const int gb = gbs;
  // exclusive scan of hist[0..256) with threads 0..255 (4 waves)
  int h = 0, x = 0;
  const int lane = t & 63, w = t >> 6;
  if (t < 256) {
    h = hist[t];
    x = h;
#pragma unroll
    for (int off = 1; off < 64; off <<= 1) {
      int v = __shfl_up(x, off);
      if (lane >= off) x += v;
    }
    if (lane == 63) wsum[w] = x;
  }
  __syncthreads();
  if (t == 0) {
    int run = 0;
#pragma unroll
    for (int j = 0; j < 4; ++j) {
      int v = wsum[j];
      wsum[j] = run;
      run += v;
    }
  }
  __syncthreads();
  if (t < 256) {
    int excl = wsum[w] + x - h;
    rowcur[t] = excl;
    int node = bk * 256 + t;
    if (node < N) {
      rowptr[node] = gb + excl;
      dinv[node] = rsqrtf((float)h + 1.0f);
    }
  }
  if (bk == nb - 1 && t == 0) rowptr[N] = E;
  __syncthreads();
  for (int i = t; i < cnt; i += 1024) {
    int rec = ebuck[base + i];
    int p = atomicAdd(&rowcur[(rec >> 17) & BMASK], 1);
    esrc[gb + p] = rec & 0x1FFFF;
  }
}

// H[N,64](fp16) = (X[N,K] @ W[K,64]) * dinv[row], via mfma_f32_16x16x32_f16.
template <int K, bool IN_HALF>
__global__ __launch_bounds__(256) void gemm_mfma(const void* __restrict__ Xin,
                                                 const float* __restrict__ W,
                                                 const float* __restrict__ dinv,
                                                 __half* __restrict__ H, int N) {
  __shared__ __align__(16) unsigned char sA[128 * K * 2];
  __shared__ __align__(16) unsigned char sB[64 * K * 2];
  const int t = threadIdx.x;
  const int brow = blockIdx.x * 128;
  constexpr int CH = K / 8;
  for (int idx = t; idx < 128 * CH; idx += 256) {
    int r = idx / CH, c = idx - r * CH;
    int row = brow + r;
    if (row >= N) row = N - 1;
    unsigned int off = (unsigned int)((r * K + c * 8) * 2) ^ ((r & 7) << 4);
    uint4 pk;
    if constexpr (IN_HALF) {
      pk = *reinterpret_cast<const uint4*>((const __half*)Xin + (size_t)row * K + c * 8);
    } else {
      const float4* xp =
          reinterpret_cast<const float4*>((const float*)Xin + (size_t)row * K + c * 8);
      float4 f0 = xp[0], f1 = xp[1];
      pk.x = pack2(f0.x, f0.y);
      pk.y = pack2(f0.z, f0.w);
      pk.z = pack2(f1.x, f1.y);
      pk.w = pack2(f1.z, f1.w);
    }
    *reinterpret_cast<uint4*>(sA + off) = pk;
  }
  for (int idx = t; idx < K * 64; idx += 256) {
    int k = idx >> 6, n = idx & 63;
    __half h = __float2half_rn(W[idx]);
    unsigned int off = (unsigned int)((n * K + k) * 2) ^ ((n & 7) << 4);
    *reinterpret_cast<unsigned short*>(sB + off) =
        *reinterpret_cast<unsigned short*>(&h);
  }
  __syncthreads();

  const int wv = t >> 6, l = t & 63;
  const int lr = l & 15;
  const int lk = (l >> 4) * 8;
  f32x4 acc[2][4] = {};
#pragma unroll
  for (int ks = 0; ks < K / 32; ++ks) {
    f16x8 af[2], bf[4];
#pragma unroll
    for (int m = 0; m < 2; ++m) {
      int r = wv * 32 + m * 16 + lr;
      unsigned int off = (unsigned int)((r * K + ks * 32 + lk) * 2) ^ ((r & 7) << 4);
      af[m] = *reinterpret_cast<const f16x8*>(sA + off);
    }
#pragma unroll
    for (int n = 0; n < 4; ++n) {
      int cc = n * 16 + lr;
      unsigned int off = (unsigned int)((cc * K + ks * 32 + lk) * 2) ^ ((cc & 7) << 4);
      bf[n] = *reinterpret_cast<const f16x8*>(sB + off);
    }
#pragma unroll
    for (int m = 0; m < 2; ++m)
#pragma unroll
      for (int n = 0; n < 4; ++n)
        acc[m][n] = __builtin_amdgcn_mfma_f32_16x16x32_f16(af[m], bf[n], acc[m][n],
                                                           0, 0, 0);
  }
#pragma unroll
  for (int m = 0; m < 2; ++m) {
#pragma unroll
    for (int j = 0; j < 4; ++j) {
      int row = brow + wv * 32 + m * 16 + (l >> 4) * 4 + j;
      if (row < N) {
        float di = dinv[row];
#pragma unroll
        for (int n = 0; n < 4; ++n) {
          float v = acc[m][n][j] * di;
          H[(size_t)row * 64 + n * 16 + lr] = __float2half_rn(v);
        }
      }
    }
  }
}

// Fused agg1 + gemm2: per block (16 nodes), aggregate y1 = relu(GCN1) into
// a 16x64 fp16 LDS tile, then wave 0 computes hs2 = (y1 @ W2) * dinv.
__global__ __launch_bounds__(256) void agg_gemm_kernel(
    const __half* __restrict__ hs, const int* __restrict__ rowptr,
    const int* __restrict__ esrc, const float* __restrict__ dinv,
    const float* __restrict__ b, const float* __restrict__ W2,
    __half* __restrict__ H2, int N) {
  __shared__ __align__(16) unsigned char sY[16 * 64 * 2];
  __shared__ __align__(16) unsigned char sW[64 * 64 * 2];
  const int t = threadIdx.x;
  for (int idx = t; idx < 64 * 64; idx += 256) {
    int k = idx >> 6, n = idx & 63;
    __half h = __float2half_rn(W2[idx]);
    unsigned int off = (unsigned int)((n * 64 + k) * 2) ^ ((n & 7) << 4);
    *reinterpret_cast<unsigned short*>(sW + off) =
        *reinterpret_cast<unsigned short*>(&h);
  }

  const int wv = t >> 6;
  const int lane = t & 63;
  const int nid = lane >> 4;
  const int g = (lane >> 3) & 1;
  const int cl = lane & 7;
  const int nodeL = wv * 4 + nid;
  const int node = blockIdx.x * 16 + nodeL;
  const unsigned int choff = (unsigned int)cl << 4;
  const unsigned char* __restrict__ hb = (const unsigned char*)hs;
  int beg = 0, end = 0;
  if (node < N) {
    beg = rowptr[node];
    end = rowptr[node + 1];
  }
  __half2 accA[4] = {{0.f, 0.f}, {0.f, 0.f}, {0.f, 0.f}, {0.f, 0.f}};
  __half2 accB[4] = {{0.f, 0.f}, {0.f, 0.f}, {0.f, 0.f}, {0.f, 0.f}};
  int k = beg + g;
  while (k < end) {
    int s0 = esrc[min(k,     end - 1)];
    int s1 = esrc[min(k + 2, end - 1)];
    int s2 = esrc[min(k + 4, end - 1)];
    int s3 = esrc[min(k + 6, end - 1)];
    uint4 v0 = *reinterpret_cast<const uint4*>(hb + (((unsigned int)s0 << 7) + choff));
    uint4 v1 = *reinterpret_cast<const uint4*>(hb + (((unsigned int)s1 << 7) + choff));
    uint4 v2 = *reinterpret_cast<const uint4*>(hb + (((unsigned int)s2 << 7) + choff));
    uint4 v3 = *reinterpret_cast<const uint4*>(hb + (((unsigned int)s3 << 7) + choff));
    {
      accA[0] = h2add(accA[0], bcast_h2(v0.x));
      accA[1] = h2add(accA[1], bcast_h2(v0.y));
      accA[2] = h2add(accA[2], bcast_h2(v0.z));
      accA[3] = h2add(accA[3], bcast_h2(v0.w));
    }
    if (k + 2 < end) {
      accB[0] = h2add(accB[0], bcast_h2(v1.x));
      accB[1] = h2add(accB[1], bcast_h2(v1.y));
      accB[2] = h2add(accB[2], bcast_h2(v1.z));
      accB[3] = h2add(accB[3], bcast_h2(v1.w));
    }
    if (k + 4 < end) {
      accA[0] = h2add(accA[0], bcast_h2(v2.x));
      accA[1] = h2add(accA[1], bcast_h2(v2.y));
      accA[2] = h2add(accA[2], bcast_h2(v2.z));
      accA[3] = h2add(accA[3], bcast_h2(v2.w));
    }
    if (k + 6 < end) {
      accB[0] = h2add(accB[0], bcast_h2(v3.x));
      accB[1] = h2add(accB[1], bcast_h2(v3.y));
      accB[2] = h2add(accB[2], bcast_h2(v3.z));
      accB[3] = h2add(accB[3], bcast_h2(v3.w));
    }
    k += 8;
  }
#pragma unroll
  for (int r = 0; r < 4; ++r) accA[r] = h2add(accA[r], accB[r]);
#pragma unroll
  for (int r = 0; r < 4; ++r) {
    int u = __shfl_xor(*reinterpret_cast<int*>(&accA[r]), 8);
    accA[r] = h2add(accA[r], *reinterpret_cast<__half2*>(&u));
  }
  if (g == 0 && node < N) {
    uint4 sv = *reinterpret_cast<const uint4*>(hb + (((unsigned int)node << 7) + choff));
    float di = dinv[node];
    const float4* bv = reinterpret_cast<const float4*>(b);
    float4 b0 = bv[cl * 2], b1 = bv[cl * 2 + 1];
    float r[8];
#pragma unroll
    for (int q = 0; q < 4; ++q) {
      float2 av = __half22float2(accA[q]);
      float2 sf = __half22float2(bcast_h2((&sv.x)[q]));
      r[2 * q]     = (av.x + sf.x) * di;
      r[2 * q + 1] = (av.y + sf.y) * di;
    }
    r[0] += b0.x; r[1] += b0.y; r[2] += b0.z; r[3] += b0.w;
    r[4] += b1.x; r[5] += b1.y; r[6] += b1.z; r[7] += b1.w;
#pragma unroll
    for (int q = 0; q < 8; ++q) r[q] = fmaxf(r[q], 0.f);   // relu (layer 1)
    uint4 pk;
    pk.x = pack2(r[0], r[1]);
    pk.y = pack2(r[2], r[3]);
    pk.z = pack2(r[4], r[5]);
    pk.w = pack2(r[6], r[7]);
    unsigned int off = (unsigned int)((nodeL * 64 + cl * 8) * 2) ^ ((nodeL & 7) << 4);
    *reinterpret_cast<uint4*>(sY + off) = pk;
  }
  __syncthreads();
  if (wv == 0) {
    const int lr = lane & 15;
    const int lk = (lane >> 4) * 8;
    f32x4 acc[4] = {};
#pragma unroll
    for (int ks = 0; ks < 2; ++ks) {
      unsigned int aoff = (unsigned int)((lr * 64 + ks * 32 + lk) * 2) ^ ((lr & 7) << 4);
      f16x8 af = *reinterpret_cast<const f16x8*>(sY + aoff);
#pragma unroll
      for (int n = 0; n < 4; ++n) {
        int cc = n * 16 + lr;
        unsigned int boff = (unsigned int)((cc * 64 + ks * 32 + lk) * 2) ^ ((cc & 7) << 4);
        f16x8 bf = *reinterpret_cast<const f16x8*>(sW + boff);
        acc[n] = __builtin_amdgcn_mfma_f32_16x16x32_f16(af, bf, acc[n], 0, 0, 0);
      }
    }
#pragma unroll
    for (int j = 0; j < 4; ++j) {
      int rowL = (lane >> 4) * 4 + j;
      int row = blockIdx.x * 16 + rowL;
      if (row < N) {
        float di = dinv[row];
#pragma unroll
        for (int n = 0; n < 4; ++n) {
          float v = acc[n][j] * di;
          H2[(size_t)row * 64 + n * 16 + lr] = __float2half_rn(v);
        }
      }
    }
  }
}

// Final aggregation (layer 2): out fp32.
__global__ __launch_bounds__(256) void agg_kernel(const __half* __restrict__ hs,
                                                  const int* __restrict__ rowptr,
                                                  const int* __restrict__ esrc,
                                                  const float* __restrict__ dinv,
                                                  const float* __restrict__ b,
                                                  float* __restrict__ outv, int N) {
  const int wv = threadIdx.x >> 6;
  const int lane = threadIdx.x & 63;
  const int nid = lane >> 4;
  const int g = (lane >> 3) & 1;
  const int cl = lane & 7;
  const int node = blockIdx.x * 16 + wv * 4 + nid;
  const unsigned int choff = (unsigned int)cl << 4;
  const unsigned char* __restrict__ hb = (const unsigned char*)hs;
  int beg = 0, end = 0;
  if (node < N) {
    beg = rowptr[node];
    end = rowptr[node + 1];
  }
  __half2 accA[4] = {{0.f, 0.f}, {0.f, 0.f}, {0.f, 0.f}, {0.f, 0.f}};
  __half2 accB[4] = {{0.f, 0.f}, {0.f, 0.f}, {0.f, 0.f}, {0.f, 0.f}};
  int k = beg + g;
  while (k < end) {
    int s0 = esrc[min(k,     end - 1)];
    int s1 = esrc[min(k + 2, end - 1)];
    int s2 = esrc[min(k + 4, end - 1)];
    int s3 = esrc[min(k + 6, end - 1)];
    uint4 v0 = *reinterpret_cast<const uint4*>(hb + (((unsigned int)s0 << 7) + choff));
    uint4 v1 = *reinterpret_cast<const uint4*>(hb + (((unsigned int)s1 << 7) + choff));
    uint4 v2 = *reinterpret_cast<const uint4*>(hb + (((unsigned int)s2 << 7) + choff));
    uint4 v3 = *reinterpret_cast<const uint4*>(hb + (((unsigned int)s3 << 7) + choff));
    {
      accA[0] = h2add(accA[0], bcast_h2(v0.x));
      accA[1] = h2add(accA[1], bcast_h2(v0.y));
      accA[2] = h2add(accA[2], bcast_h2(v0.z));
      accA[3] = h2add(accA[3], bcast_h2(v0.w));
    }
    if (k + 2 < end) {
      accB[0] = h2add(accB[0], bcast_h2(v1.x));
      accB[1] = h2add(accB[1], bcast_h2(v1.y));
      accB[2] = h2add(accB[2], bcast_h2(v1.z));
      accB[3] = h2add(accB[3], bcast_h2(v1.w));
    }
    if (k + 4 < end) {
      accA[0] = h2add(accA[0], bcast_h2(v2.x));
      accA[1] = h2add(accA[1], bcast_h2(v2.y));
      accA[2] = h2add(accA[2], bcast_h2(v2.z));
      accA[3] = h2add(accA[3], bcast_h2(v2.w));
    }
    if (k + 6 < end) {
      accB[0] = h2add(accB[0], bcast_h2(v3.x));
      accB[1] = h2add(accB[1], bcast_h2(v3.y));
      accB[2] = h2add(accB[2], bcast_h2(v3.z));
      accB[3] = h2add(accB[3], bcast_h2(v3.w));
    }
    k += 8;
  }
#pragma unroll
  for (int r = 0; r < 4; ++r) accA[r] = h2add(accA[r], accB[r]);
#pragma unroll
  for (int r = 0; r < 4; ++r) {
    int u = __shfl_xor(*reinterpret_cast<int*>(&accA[r]), 8);
    accA[r] = h2add(accA[r], *reinterpret_cast<__half2*>(&u));
  }
  if (g == 0 && node < N) {
    uint4 sv = *reinterpret_cast<const uint4*>(hb + (((unsigned int)node << 7) + choff));
    float di = dinv[node];
    const float4* bv = reinterpret_cast<const float4*>(b);
    float4 b0 = bv[cl * 2], b1 = bv[cl * 2 + 1];
    float r[8];
#pragma unroll
    for (int q = 0; q < 4; ++q) {
      float2 av = __half22float2(accA[q]);
      float2 sf = __half22float2(bcast_h2((&sv.x)[q]));
      r[2 * q]     = (av.x + sf.x) * di;
      r[2 * q + 1] = (av.y + sf.y) * di;
    }
    r[0] += b0.x; r[1] += b0.y; r[2] += b0.z; r[3] += b0.w;
    r[4] += b1.x; r[5] += b1.y; r[6] += b1.z; r[7] += b1.w;
    float4* ov = reinterpret_cast<float4*>(outv);
    ov[(size_t)node * 16 + cl * 2]     = make_float4(r[0], r[1], r[2], r[3]);
    ov[(size_t)node * 16 + cl * 2 + 1] = make_float4(r[4], r[5], r[6], r[7]);
  }
}

extern "C" void kernel_launch(void* const* d_in, const int* in_sizes, int n_in,
                              void* d_out, int out_size, void* d_ws, size_t ws_size,
                              hipStream_t stream) {
  const float* x  = (const float*)d_in[0];
  const int*   ei = (const int*)d_in[1];
  const float* W1 = (const float*)d_in[2];
  const float* b1 = (const float*)d_in[3];
  const float* W2 = (const float*)d_in[4];
  const float* b2 = (const float*)d_in[5];
  const int N = in_sizes[0] / 128;
  const int E = in_sizes[1] / 2;
  const int* src = ei;
  const int* dst = ei + E;
  const int nb = (N + 255) >> BSHIFT;  // 391 buckets of 256 nodes

  char* ws = (char*)d_ws;
  int*    bcursor = (int*)ws;                       // nb ints
  float*  dinv    = (float*)(ws + (1 << 20));       // N floats  @ 1MB
  int*    rowptr  = (int*)(ws + 3 * (1 << 19));     // N+1 ints  @ 1.5MB
  int*    esrc    = (int*)(ws + (1 << 21));         // E ints    @ 2MB   (6.4MB)
  int*    ebuck   = (int*)(ws + 9 * (1 << 20));     // nb*BCAP   @ 9MB   (12.8MB)
  __half* hs      = (__half*)(ws + 22 * (1 << 20)); // N*64 fp16 @ 22MB  (12.8MB)
  __half* hs2     = (__half*)(ws + 36 * (1 << 20)); // N*64 fp16 @ 36MB  (12.8MB)
  float*  out = (float*)d_out;

  // CSR build (shared by both layers)
  initcur_kernel<<<(nb + 255) / 256, 256, 0, stream>>>(bcursor, nb);
  chunksort_kernel<<<(E + CHUNK - 1) / CHUNK, 512, 0, stream>>>(src, dst, bcursor,
                                                                ebuck, E, nb);
  bucketsort_kernel<<<nb, 1024, 0, stream>>>(ebuck, bcursor, esrc, rowptr,
                                             dinv, N, E, nb);

  const int gemmGrid = (N + 127) / 128;
  const int aggGrid = (N + 15) / 16;
  // layer 1 GEMM: hs1(fp16) -> hs
  gemm_mfma<128, false><<<gemmGrid, 256, 0, stream>>>(x, W1, dinv, hs, N);
  // fused layer-1 aggregation + layer-2 GEMM: hs2(fp16)
  agg_gemm_kernel<<<aggGrid, 256, 0, stream>>>(hs, rowptr, esrc, dinv, b1, W2,
                                               hs2, N);
  // layer-2 aggregation: out fp32
  agg_kernel<<<aggGrid, 256, 0, stream>>>(hs2, rowptr, esrc, dinv, b2, out, N);
}

// Round 15
// 127.301 us; speedup vs baseline: 1.3752x; 1.0279x over previous
//
#include <hip/hip_runtime.h>
#include <hip/hip_fp16.h>

// GCN 2-layer forward. CSR via two-phase dst-sort, MFMA fp16 GEMMs,
// fp16 message tables, 4-node-per-wave gather aggregation, gemm2 fused
// into agg1. R15: chunksort v3 - no scan/staging, direct global scatter
// into per-bucket runs (CHUNK=4096, 1024 thr, 6KB LDS).

#define CHUNK 4096
#define BCAP  8192
#define NB_PAD 512
#define BSHIFT 8
#define BMASK 255

typedef _Float16 f16x8 __attribute__((ext_vector_type(8)));
typedef float f32x4 __attribute__((ext_vector_type(4)));

__device__ __forceinline__ unsigned int pack2(float a, float b) {
  __half2 h = __floats2half2_rn(a, b);
  return *reinterpret_cast<unsigned int*>(&h);
}
__device__ __forceinline__ __half2 h2add(__half2 a, __half2 b) {
  return __hadd2(a, b);
}
__device__ __forceinline__ __half2 bcast_h2(unsigned int u) {
  return *reinterpret_cast<__half2*>(&u);
}

__global__ __launch_bounds__(256) void initcur_kernel(int* __restrict__ bcursor,
                                                      int nb) {
  int i = blockIdx.x * 256 + threadIdx.x;
  if (i < nb) bcursor[i] = i * BCAP;
}

// Phase 1 (v3): per 4096-edge chunk, LDS histogram -> reserve per-bucket runs
// (1 global atomic per non-empty bucket) -> direct scatter into the runs.
// Writes land in 391 L2-resident run windows; no LDS staging, no scan.
__global__ __launch_bounds__(1024) void chunksort_kernel(
    const int* __restrict__ src, const int* __restrict__ dst,
    int* __restrict__ bcursor, int* __restrict__ ebuck, int nE, int nb) {
  __shared__ int hist[NB_PAD];
  __shared__ int gbase[NB_PAD];
  __shared__ int lcur[NB_PAD];
  const int t = threadIdx.x;
  const int e0 = blockIdx.x * CHUNK;
  const int n = min(CHUNK, nE - e0);
  if (t < NB_PAD) hist[t] = 0;
  __syncthreads();
  for (int i = t; i < n; i += 1024) atomicAdd(&hist[dst[e0 + i] >> BSHIFT], 1);
  __syncthreads();
  if (t < NB_PAD) {
    int c = hist[t];
    gbase[t] = c ? atomicAdd(&bcursor[t], c) : 0;
    lcur[t] = 0;
  }
  __syncthreads();
  for (int i = t; i < n; i += 1024) {
    int d = dst[e0 + i];
    int b = d >> BSHIFT;
    int p = atomicAdd(&lcur[b], 1);
    ebuck[gbase[b] + p] = src[e0 + i] | ((d & BMASK) << 17);
  }
}

// Phase 2: per-bucket counting sort (256 keys), direct-global scatter.
// bbase computed in-kernel as a reduction over bcursor[0..bk).
__global__ __launch_bounds__(1024) void bucketsort_kernel(
    const int* __restrict__ ebuck, const int* __restrict__ bcursor,
    int* __restrict__ esrc, int* __restrict__ rowptr,
    float* __restrict__ dinv, int N, int E, int nb) {
  __shared__ int hist[256];
  __shared__ int rowcur[256];
  __shared__ int red[1024];
  __shared__ int wsum[4];
  __shared__ int gbs;
  const int t = threadIdx.x;
  const int bk = blockIdx.x;
  const int base = bk * BCAP;
  const int cnt = bcursor[bk] - base;
  // bbase reduction: sum of counts of buckets < bk
  int partial = 0;
  for (int j = t; j < bk; j += 1024) partial += bcursor[j] - j * BCAP;
  red[t] = partial;
  if (t < 256) hist[t] = 0;
  __syncthreads();
  for (int off = 512; off > 0; off >>= 1) {
    if (t < off) red[t] += red[t + off];
    __syncthreads();
  }
  if (t == 0) gbs = red[0];
  for (int i = t; i < cnt; i += 1024)
    atomicAdd(&hist[(ebuck[base + i] >> 17) & BMASK], 1);
  __syncthreads();
  const int gb = gbs;
  // exclusive scan of hist[0..256) with threads 0..255 (4 waves)
  int h = 0, x = 0;
  const int lane = t & 63, w = t >> 6;
  if (t < 256) {
    h = hist[t];
    x = h;
#pragma unroll
    for (int off = 1; off < 64; off <<= 1) {
      int v = __shfl_up(x, off);
      if (lane >= off) x += v;
    }
    if (lane == 63) wsum[w] = x;
  }
  __syncthreads();
  if (t == 0) {
    int run = 0;
#pragma unroll
    for (int j = 0; j < 4; ++j) {
      int v = wsum[j];
      wsum[j] = run;
      run += v;
    }
  }
  __syncthreads();
  if (t < 256) {
    int excl = wsum[w] + x - h;
    rowcur[t] = excl;
    int node = bk * 256 + t;
    if (node < N) {
      rowptr[node] = gb + excl;
      dinv[node] = rsqrtf((float)h + 1.0f);
    }
  }
  if (bk == nb - 1 && t == 0) rowptr[N] = E;
  __syncthreads();
  for (int i = t; i < cnt; i += 1024) {
    int rec = ebuck[base + i];
    int p = atomicAdd(&rowcur[(rec >> 17) & BMASK], 1);
    esrc[gb + p] = rec & 0x1FFFF;
  }
}

// H[N,64](fp16) = (X[N,K] @ W[K,64]) * dinv[row], via mfma_f32_16x16x32_f16.
template <int K, bool IN_HALF>
__global__ __launch_bounds__(256) void gemm_mfma(const void* __restrict__ Xin,
                                                 const float* __restrict__ W,
                                                 const float* __restrict__ dinv,
                                                 __half* __restrict__ H, int N) {
  __shared__ __align__(16) unsigned char sA[128 * K * 2];
  __shared__ __align__(16) unsigned char sB[64 * K * 2];
  const int t = threadIdx.x;
  const int brow = blockIdx.x * 128;
  constexpr int CH = K / 8;
  for (int idx = t; idx < 128 * CH; idx += 256) {
    int r = idx / CH, c = idx - r * CH;
    int row = brow + r;
    if (row >= N) row = N - 1;
    unsigned int off = (unsigned int)((r * K + c * 8) * 2) ^ ((r & 7) << 4);
    uint4 pk;
    if constexpr (IN_HALF) {
      pk = *reinterpret_cast<const uint4*>((const __half*)Xin + (size_t)row * K + c * 8);
    } else {
      const float4* xp =
          reinterpret_cast<const float4*>((const float*)Xin + (size_t)row * K + c * 8);
      float4 f0 = xp[0], f1 = xp[1];
      pk.x = pack2(f0.x, f0.y);
      pk.y = pack2(f0.z, f0.w);
      pk.z = pack2(f1.x, f1.y);
      pk.w = pack2(f1.z, f1.w);
    }
    *reinterpret_cast<uint4*>(sA + off) = pk;
  }
  for (int idx = t; idx < K * 64; idx += 256) {
    int k = idx >> 6, n = idx & 63;
    __half h = __float2half_rn(W[idx]);
    unsigned int off = (unsigned int)((n * K + k) * 2) ^ ((n & 7) << 4);
    *reinterpret_cast<unsigned short*>(sB + off) =
        *reinterpret_cast<unsigned short*>(&h);
  }
  __syncthreads();

  const int wv = t >> 6, l = t & 63;
  const int lr = l & 15;
  const int lk = (l >> 4) * 8;
  f32x4 acc[2][4] = {};
#pragma unroll
  for (int ks = 0; ks < K / 32; ++ks) {
    f16x8 af[2], bf[4];
#pragma unroll
    for (int m = 0; m < 2; ++m) {
      int r = wv * 32 + m * 16 + lr;
      unsigned int off = (unsigned int)((r * K + ks * 32 + lk) * 2) ^ ((r & 7) << 4);
      af[m] = *reinterpret_cast<const f16x8*>(sA + off);
    }
#pragma unroll
    for (int n = 0; n < 4; ++n) {
      int cc = n * 16 + lr;
      unsigned int off = (unsigned int)((cc * K + ks * 32 + lk) * 2) ^ ((cc & 7) << 4);
      bf[n] = *reinterpret_cast<const f16x8*>(sB + off);
    }
#pragma unroll
    for (int m = 0; m < 2; ++m)
#pragma unroll
      for (int n = 0; n < 4; ++n)
        acc[m][n] = __builtin_amdgcn_mfma_f32_16x16x32_f16(af[m], bf[n], acc[m][n],
                                                           0, 0, 0);
  }
#pragma unroll
  for (int m = 0; m < 2; ++m) {
#pragma unroll
    for (int j = 0; j < 4; ++j) {
      int row = brow + wv * 32 + m * 16 + (l >> 4) * 4 + j;
      if (row < N) {
        float di = dinv[row];
#pragma unroll
        for (int n = 0; n < 4; ++n) {
          float v = acc[m][n][j] * di;
          H[(size_t)row * 64 + n * 16 + lr] = __float2half_rn(v);
        }
      }
    }
  }
}

// Fused agg1 + gemm2: per block (16 nodes), aggregate y1 = relu(GCN1) into
// a 16x64 fp16 LDS tile, then wave 0 computes hs2 = (y1 @ W2) * dinv.
__global__ __launch_bounds__(256) void agg_gemm_kernel(
    const __half* __restrict__ hs, const int* __restrict__ rowptr,
    const int* __restrict__ esrc, const float* __restrict__ dinv,
    const float* __restrict__ b, const float* __restrict__ W2,
    __half* __restrict__ H2, int N) {
  __shared__ __align__(16) unsigned char sY[16 * 64 * 2];
  __shared__ __align__(16) unsigned char sW[64 * 64 * 2];
  const int t = threadIdx.x;
  for (int idx = t; idx < 64 * 64; idx += 256) {
    int k = idx >> 6, n = idx & 63;
    __half h = __float2half_rn(W2[idx]);
    unsigned int off = (unsigned int)((n * 64 + k) * 2) ^ ((n & 7) << 4);
    *reinterpret_cast<unsigned short*>(sW + off) =
        *reinterpret_cast<unsigned short*>(&h);
  }

  const int wv = t >> 6;
  const int lane = t & 63;
  const int nid = lane >> 4;
  const int g = (lane >> 3) & 1;
  const int cl = lane & 7;
  const int nodeL = wv * 4 + nid;
  const int node = blockIdx.x * 16 + nodeL;
  const unsigned int choff = (unsigned int)cl << 4;
  const unsigned char* __restrict__ hb = (const unsigned char*)hs;
  int beg = 0, end = 0;
  if (node < N) {
    beg = rowptr[node];
    end = rowptr[node + 1];
  }
  __half2 accA[4] = {{0.f, 0.f}, {0.f, 0.f}, {0.f, 0.f}, {0.f, 0.f}};
  __half2 accB[4] = {{0.f, 0.f}, {0.f, 0.f}, {0.f, 0.f}, {0.f, 0.f}};
  int k = beg + g;
  while (k < end) {
    int s0 = esrc[min(k,     end - 1)];
    int s1 = esrc[min(k + 2, end - 1)];
    int s2 = esrc[min(k + 4, end - 1)];
    int s3 = esrc[min(k + 6, end - 1)];
    uint4 v0 = *reinterpret_cast<const uint4*>(hb + (((unsigned int)s0 << 7) + choff));
    uint4 v1 = *reinterpret_cast<const uint4*>(hb + (((unsigned int)s1 << 7) + choff));
    uint4 v2 = *reinterpret_cast<const uint4*>(hb + (((unsigned int)s2 << 7) + choff));
    uint4 v3 = *reinterpret_cast<const uint4*>(hb + (((unsigned int)s3 << 7) + choff));
    {
      accA[0] = h2add(accA[0], bcast_h2(v0.x));
      accA[1] = h2add(accA[1], bcast_h2(v0.y));
      accA[2] = h2add(accA[2], bcast_h2(v0.z));
      accA[3] = h2add(accA[3], bcast_h2(v0.w));
    }
    if (k + 2 < end) {
      accB[0] = h2add(accB[0], bcast_h2(v1.x));
      accB[1] = h2add(accB[1], bcast_h2(v1.y));
      accB[2] = h2add(accB[2], bcast_h2(v1.z));
      accB[3] = h2add(accB[3], bcast_h2(v1.w));
    }
    if (k + 4 < end) {
      accA[0] = h2add(accA[0], bcast_h2(v2.x));
      accA[1] = h2add(accA[1], bcast_h2(v2.y));
      accA[2] = h2add(accA[2], bcast_h2(v2.z));
      accA[3] = h2add(accA[3], bcast_h2(v2.w));
    }
    if (k + 6 < end) {
      accB[0] = h2add(accB[0], bcast_h2(v3.x));
      accB[1] = h2add(accB[1], bcast_h2(v3.y));
      accB[2] = h2add(accB[2], bcast_h2(v3.z));
      accB[3] = h2add(accB[3], bcast_h2(v3.w));
    }
    k += 8;
  }
#pragma unroll
  for (int r = 0; r < 4; ++r) accA[r] = h2add(accA[r], accB[r]);
#pragma unroll
  for (int r = 0; r < 4; ++r) {
    int u = __shfl_xor(*reinterpret_cast<int*>(&accA[r]), 8);
    accA[r] = h2add(accA[r], *reinterpret_cast<__half2*>(&u));
  }
  if (g == 0 && node < N) {
    uint4 sv = *reinterpret_cast<const uint4*>(hb + (((unsigned int)node << 7) + choff));
    float di = dinv[node];
    const float4* bv = reinterpret_cast<const float4*>(b);
    float4 b0 = bv[cl * 2], b1 = bv[cl * 2 + 1];
    float r[8];
#pragma unroll
    for (int q = 0; q < 4; ++q) {
      float2 av = __half22float2(accA[q]);
      float2 sf = __half22float2(bcast_h2((&sv.x)[q]));
      r[2 * q]     = (av.x + sf.x) * di;
      r[2 * q + 1] = (av.y + sf.y) * di;
    }
    r[0] += b0.x; r[1] += b0.y; r[2] += b0.z; r[3] += b0.w;
    r[4] += b1.x; r[5] += b1.y; r[6] += b1.z; r[7] += b1.w;
#pragma unroll
    for (int q = 0; q < 8; ++q) r[q] = fmaxf(r[q], 0.f);   // relu (layer 1)
    uint4 pk;
    pk.x = pack2(r[0], r[1]);
    pk.y = pack2(r[2], r[3]);
    pk.z = pack2(r[4], r[5]);
    pk.w = pack2(r[6], r[7]);
    unsigned int off = (unsigned int)((nodeL * 64 + cl * 8) * 2) ^ ((nodeL & 7) << 4);
    *reinterpret_cast<uint4*>(sY + off) = pk;
  }
  __syncthreads();
  if (wv == 0) {
    const int lr = lane & 15;
    const int lk = (lane >> 4) * 8;
    f32x4 acc[4] = {};
#pragma unroll
    for (int ks = 0; ks < 2; ++ks) {
      unsigned int aoff = (unsigned int)((lr * 64 + ks * 32 + lk) * 2) ^ ((lr & 7) << 4);
      f16x8 af = *reinterpret_cast<const f16x8*>(sY + aoff);
#pragma unroll
      for (int n = 0; n < 4; ++n) {
        int cc = n * 16 + lr;
        unsigned int boff = (unsigned int)((cc * 64 + ks * 32 + lk) * 2) ^ ((cc & 7) << 4);
        f16x8 bf = *reinterpret_cast<const f16x8*>(sW + boff);
        acc[n] = __builtin_amdgcn_mfma_f32_16x16x32_f16(af, bf, acc[n], 0, 0, 0);
      }
    }
#pragma unroll
    for (int j = 0; j < 4; ++j) {
      int rowL = (lane >> 4) * 4 + j;
      int row = blockIdx.x * 16 + rowL;
      if (row < N) {
        float di = dinv[row];
#pragma unroll
        for (int n = 0; n < 4; ++n) {
          float v = acc[n][j] * di;
          H2[(size_t)row * 64 + n * 16 + lr] = __float2half_rn(v);
        }
      }
    }
  }
}

// Final aggregation (layer 2): out fp32.
__global__ __launch_bounds__(256) void agg_kernel(const __half* __restrict__ hs,
                                                  const int* __restrict__ rowptr,
                                                  const int* __restrict__ esrc,
                                                  const float* __restrict__ dinv,
                                                  const float* __restrict__ b,
                                                  float* __restrict__ outv, int N) {
  const int wv = threadIdx.x >> 6;
  const int lane = threadIdx.x & 63;
  const int nid = lane >> 4;
  const int g = (lane >> 3) & 1;
  const int cl = lane & 7;
  const int node = blockIdx.x * 16 + wv * 4 + nid;
  const unsigned int choff = (unsigned int)cl << 4;
  const unsigned char* __restrict__ hb = (const unsigned char*)hs;
  int beg = 0, end = 0;
  if (node < N) {
    beg = rowptr[node];
    end = rowptr[node + 1];
  }
  __half2 accA[4] = {{0.f, 0.f}, {0.f, 0.f}, {0.f, 0.f}, {0.f, 0.f}};
  __half2 accB[4] = {{0.f, 0.f}, {0.f, 0.f}, {0.f, 0.f}, {0.f, 0.f}};
  int k = beg + g;
  while (k < end) {
    int s0 = esrc[min(k,     end - 1)];
    int s1 = esrc[min(k + 2, end - 1)];
    int s2 = esrc[min(k + 4, end - 1)];
    int s3 = esrc[min(k + 6, end - 1)];
    uint4 v0 = *reinterpret_cast<const uint4*>(hb + (((unsigned int)s0 << 7) + choff));
    uint4 v1 = *reinterpret_cast<const uint4*>(hb + (((unsigned int)s1 << 7) + choff));
    uint4 v2 = *reinterpret_cast<const uint4*>(hb + (((unsigned int)s2 << 7) + choff));
    uint4 v3 = *reinterpret_cast<const uint4*>(hb + (((unsigned int)s3 << 7) + choff));
    {
      accA[0] = h2add(accA[0], bcast_h2(v0.x));
      accA[1] = h2add(accA[1], bcast_h2(v0.y));
      accA[2] = h2add(accA[2], bcast_h2(v0.z));
      accA[3] = h2add(accA[3], bcast_h2(v0.w));
    }
    if (k + 2 < end) {
      accB[0] = h2add(accB[0], bcast_h2(v1.x));
      accB[1] = h2add(accB[1], bcast_h2(v1.y));
      accB[2] = h2add(accB[2], bcast_h2(v1.z));
      accB[3] = h2add(accB[3], bcast_h2(v1.w));
    }
    if (k + 4 < end) {
      accA[0] = h2add(accA[0], bcast_h2(v2.x));
      accA[1] = h2add(accA[1], bcast_h2(v2.y));
      accA[2] = h2add(accA[2], bcast_h2(v2.z));
      accA[3] = h2add(accA[3], bcast_h2(v2.w));
    }
    if (k + 6 < end) {
      accB[0] = h2add(accB[0], bcast_h2(v3.x));
      accB[1] = h2add(accB[1], bcast_h2(v3.y));
      accB[2] = h2add(accB[2], bcast_h2(v3.z));
      accB[3] = h2add(accB[3], bcast_h2(v3.w));
    }
    k += 8;
  }
#pragma unroll
  for (int r = 0; r < 4; ++r) accA[r] = h2add(accA[r], accB[r]);
#pragma unroll
  for (int r = 0; r < 4; ++r) {
    int u = __shfl_xor(*reinterpret_cast<int*>(&accA[r]), 8);
    accA[r] = h2add(accA[r], *reinterpret_cast<__half2*>(&u));
  }
  if (g == 0 && node < N) {
    uint4 sv = *reinterpret_cast<const uint4*>(hb + (((unsigned int)node << 7) + choff));
    float di = dinv[node];
    const float4* bv = reinterpret_cast<const float4*>(b);
    float4 b0 = bv[cl * 2], b1 = bv[cl * 2 + 1];
    float r[8];
#pragma unroll
    for (int q = 0; q < 4; ++q) {
      float2 av = __half22float2(accA[q]);
      float2 sf = __half22float2(bcast_h2((&sv.x)[q]));
      r[2 * q]     = (av.x + sf.x) * di;
      r[2 * q + 1] = (av.y + sf.y) * di;
    }
    r[0] += b0.x; r[1] += b0.y; r[2] += b0.z; r[3] += b0.w;
    r[4] += b1.x; r[5] += b1.y; r[6] += b1.z; r[7] += b1.w;
    float4* ov = reinterpret_cast<float4*>(outv);
    ov[(size_t)node * 16 + cl * 2]     = make_float4(r[0], r[1], r[2], r[3]);
    ov[(size_t)node * 16 + cl * 2 + 1] = make_float4(r[4], r[5], r[6], r[7]);
  }
}

extern "C" void kernel_launch(void* const* d_in, const int* in_sizes, int n_in,
                              void* d_out, int out_size, void* d_ws, size_t ws_size,
                              hipStream_t stream) {
  const float* x  = (const float*)d_in[0];
  const int*   ei = (const int*)d_in[1];
  const float* W1 = (const float*)d_in[2];
  const float* b1 = (const float*)d_in[3];
  const float* W2 = (const float*)d_in[4];
  const float* b2 = (const float*)d_in[5];
  const int N = in_sizes[0] / 128;
  const int E = in_sizes[1] / 2;
  const int* src = ei;
  const int* dst = ei + E;
  const int nb = (N + 255) >> BSHIFT;  // 391 buckets of 256 nodes

  char* ws = (char*)d_ws;
  int*    bcursor = (int*)ws;                       // nb ints
  float*  dinv    = (float*)(ws + (1 << 20));       // N floats  @ 1MB
  int*    rowptr  = (int*)(ws + 3 * (1 << 19));     // N+1 ints  @ 1.5MB
  int*    esrc    = (int*)(ws + (1 << 21));         // E ints    @ 2MB   (6.4MB)
  int*    ebuck   = (int*)(ws + 9 * (1 << 20));     // nb*BCAP   @ 9MB   (12.8MB)
  __half* hs      = (__half*)(ws + 22 * (1 << 20)); // N*64 fp16 @ 22MB  (12.8MB)
  __half* hs2     = (__half*)(ws + 36 * (1 << 20)); // N*64 fp16 @ 36MB  (12.8MB)
  float*  out = (float*)d_out;

  // CSR build (shared by both layers)
  initcur_kernel<<<(nb + 255) / 256, 256, 0, stream>>>(bcursor, nb);
  chunksort_kernel<<<(E + CHUNK - 1) / CHUNK, 1024, 0, stream>>>(src, dst, bcursor,
                                                                 ebuck, E, nb);
  bucketsort_kernel<<<nb, 1024, 0, stream>>>(ebuck, bcursor, esrc, rowptr,
                                             dinv, N, E, nb);

  const int gemmGrid = (N + 127) / 128;
  const int aggGrid = (N + 15) / 16;
  // layer 1 GEMM: hs1(fp16) -> hs
  gemm_mfma<128, false><<<gemmGrid, 256, 0, stream>>>(x, W1, dinv, hs, N);
  // fused layer-1 aggregation + layer-2 GEMM: hs2(fp16)
  agg_gemm_kernel<<<aggGrid, 256, 0, stream>>>(hs, rowptr, esrc, dinv, b1, W2,
                                               hs2, N);
  // layer-2 aggregation: out fp32
  agg_kernel<<<aggGrid, 256, 0, stream>>>(hs2, rowptr, esrc, dinv, b2, out, N);
}

// Round 16
// 124.746 us; speedup vs baseline: 1.4034x; 1.0205x over previous
//
#include <hip/hip_runtime.h>
#include <hip/hip_fp16.h>

// GCN 2-layer forward. CSR via two-phase dst-sort, MFMA fp16 GEMMs,
// fp16 message tables, 4-node-per-wave gather aggregation, gemm2 fused
// into agg1. R16: gemm1 BM 128->64 (LDS 48->32KB, 2 blocks/CU).

#define CHUNK 4096
#define BCAP  8192
#define NB_PAD 512
#define BSHIFT 8
#define BMASK 255

typedef _Float16 f16x8 __attribute__((ext_vector_type(8)));
typedef float f32x4 __attribute__((ext_vector_type(4)));

__device__ __forceinline__ unsigned int pack2(float a, float b) {
  __half2 h = __floats2half2_rn(a, b);
  return *reinterpret_cast<unsigned int*>(&h);
}
__device__ __forceinline__ __half2 h2add(__half2 a, __half2 b) {
  return __hadd2(a, b);
}
__device__ __forceinline__ __half2 bcast_h2(unsigned int u) {
  return *reinterpret_cast<__half2*>(&u);
}

__global__ __launch_bounds__(256) void initcur_kernel(int* __restrict__ bcursor,
                                                      int nb) {
  int i = blockIdx.x * 256 + threadIdx.x;
  if (i < nb) bcursor[i] = i * BCAP;
}

// Phase 1 (v3): per 4096-edge chunk, LDS histogram -> reserve per-bucket runs
// (1 global atomic per non-empty bucket) -> direct scatter into the runs.
__global__ __launch_bounds__(1024) void chunksort_kernel(
    const int* __restrict__ src, const int* __restrict__ dst,
    int* __restrict__ bcursor, int* __restrict__ ebuck, int nE, int nb) {
  __shared__ int hist[NB_PAD];
  __shared__ int gbase[NB_PAD];
  __shared__ int lcur[NB_PAD];
  const int t = threadIdx.x;
  const int e0 = blockIdx.x * CHUNK;
  const int n = min(CHUNK, nE - e0);
  if (t < NB_PAD) hist[t] = 0;
  __syncthreads();
  for (int i = t; i < n; i += 1024) atomicAdd(&hist[dst[e0 + i] >> BSHIFT], 1);
  __syncthreads();
  if (t < NB_PAD) {
    int c = hist[t];
    gbase[t] = c ? atomicAdd(&bcursor[t], c) : 0;
    lcur[t] = 0;
  }
  __syncthreads();
  for (int i = t; i < n; i += 1024) {
    int d = dst[e0 + i];
    int b = d >> BSHIFT;
    int p = atomicAdd(&lcur[b], 1);
    ebuck[gbase[b] + p] = src[e0 + i] | ((d & BMASK) << 17);
  }
}

// Phase 2: per-bucket counting sort (256 keys), direct-global scatter.
__global__ __launch_bounds__(1024) void bucketsort_kernel(
    const int* __restrict__ ebuck, const int* __restrict__ bcursor,
    int* __restrict__ esrc, int* __restrict__ rowptr,
    float* __restrict__ dinv, int N, int E, int nb) {
  __shared__ int hist[256];
  __shared__ int rowcur[256];
  __shared__ int red[1024];
  __shared__ int wsum[4];
  __shared__ int gbs;
  const int t = threadIdx.x;
  const int bk = blockIdx.x;
  const int base = bk * BCAP;
  const int cnt = bcursor[bk] - base;
  int partial = 0;
  for (int j = t; j < bk; j += 1024) partial += bcursor[j] - j * BCAP;
  red[t] = partial;
  if (t < 256) hist[t] = 0;
  __syncthreads();
  for (int off = 512; off > 0; off >>= 1) {
    if (t < off) red[t] += red[t + off];
    __syncthreads();
  }
  if (t == 0) gbs = red[0];
  for (int i = t; i < cnt; i += 1024)
    atomicAdd(&hist[(ebuck[base + i] >> 17) & BMASK], 1);
  __syncthreads();
  const int gb = gbs;
  int h = 0, x = 0;
  const int lane = t & 63, w = t >> 6;
  if (t < 256) {
    h = hist[t];
    x = h;
#pragma unroll
    for (int off = 1; off < 64; off <<= 1) {
      int v = __shfl_up(x, off);
      if (lane >= off) x += v;
    }
    if (lane == 63) wsum[w] = x;
  }
  __syncthreads();
  if (t == 0) {
    int run = 0;
#pragma unroll
    for (int j = 0; j < 4; ++j) {
      int v = wsum[j];
      wsum[j] = run;
      run += v;
    }
  }
  __syncthreads();
  if (t < 256) {
    int excl = wsum[w] + x - h;
    rowcur[t] = excl;
    int node = bk * 256 + t;
    if (node < N) {
      rowptr[node] = gb + excl;
      dinv[node] = rsqrtf((float)h + 1.0f);
    }
  }
  if (bk == nb - 1 && t == 0) rowptr[N] = E;
  __syncthreads();
  for (int i = t; i < cnt; i += 1024) {
    int rec = ebuck[base + i];
    int p = atomicAdd(&rowcur[(rec >> 17) & BMASK], 1);
    esrc[gb + p] = rec & 0x1FFFF;
  }
}

// H[N,64](fp16) = (X[N,K] @ W[K,64]) * dinv[row], via mfma_f32_16x16x32_f16.
// BM=64: sA 16KB + sB 16KB = 32KB -> 2 blocks/CU. Wave wv owns rows
// wv*16..wv*16+15 (one 16-row x 64-col strip, 4 n-tiles).
template <int K>
__global__ __launch_bounds__(256) void gemm_mfma(const float* __restrict__ Xin,
                                                 const float* __restrict__ W,
                                                 const float* __restrict__ dinv,
                                                 __half* __restrict__ H, int N) {
  __shared__ __align__(16) unsigned char sA[64 * K * 2];
  __shared__ __align__(16) unsigned char sB[64 * K * 2];
  const int t = threadIdx.x;
  const int brow = blockIdx.x * 64;
  constexpr int CH = K / 8;
  for (int idx = t; idx < 64 * CH; idx += 256) {
    int r = idx / CH, c = idx - r * CH;
    int row = brow + r;
    if (row >= N) row = N - 1;
    unsigned int off = (unsigned int)((r * K + c * 8) * 2) ^ ((r & 7) << 4);
    const float4* xp =
        reinterpret_cast<const float4*>(Xin + (size_t)row * K + c * 8);
    float4 f0 = xp[0], f1 = xp[1];
    uint4 pk;
    pk.x = pack2(f0.x, f0.y);
    pk.y = pack2(f0.z, f0.w);
    pk.z = pack2(f1.x, f1.y);
    pk.w = pack2(f1.z, f1.w);
    *reinterpret_cast<uint4*>(sA + off) = pk;
  }
  for (int idx = t; idx < K * 64; idx += 256) {
    int k = idx >> 6, n = idx & 63;
    __half h = __float2half_rn(W[idx]);
    unsigned int off = (unsigned int)((n * K + k) * 2) ^ ((n & 7) << 4);
    *reinterpret_cast<unsigned short*>(sB + off) =
        *reinterpret_cast<unsigned short*>(&h);
  }
  __syncthreads();

  const int wv = t >> 6, l = t & 63;
  const int lr = l & 15;
  const int lk = (l >> 4) * 8;
  f32x4 acc[4] = {};
#pragma unroll
  for (int ks = 0; ks < K / 32; ++ks) {
    int r = wv * 16 + lr;
    unsigned int aoff = (unsigned int)((r * K + ks * 32 + lk) * 2) ^ ((r & 7) << 4);
    f16x8 af = *reinterpret_cast<const f16x8*>(sA + aoff);
#pragma unroll
    for (int n = 0; n < 4; ++n) {
      int cc = n * 16 + lr;
      unsigned int boff = (unsigned int)((cc * K + ks * 32 + lk) * 2) ^ ((cc & 7) << 4);
      f16x8 bf = *reinterpret_cast<const f16x8*>(sB + boff);
      acc[n] = __builtin_amdgcn_mfma_f32_16x16x32_f16(af, bf, acc[n], 0, 0, 0);
    }
  }
#pragma unroll
  for (int j = 0; j < 4; ++j) {
    int row = brow + wv * 16 + (l >> 4) * 4 + j;
    if (row < N) {
      float di = dinv[row];
#pragma unroll
      for (int n = 0; n < 4; ++n) {
        float v = acc[n][j] * di;
        H[(size_t)row * 64 + n * 16 + lr] = __float2half_rn(v);
      }
    }
  }
}

// Fused agg1 + gemm2: per block (16 nodes), aggregate y1 = relu(GCN1) into
// a 16x64 fp16 LDS tile, then wave 0 computes hs2 = (y1 @ W2) * dinv.
__global__ __launch_bounds__(256) void agg_gemm_kernel(
    const __half* __restrict__ hs, const int* __restrict__ rowptr,
    const int* __restrict__ esrc, const float* __restrict__ dinv,
    const float* __restrict__ b, const float* __restrict__ W2,
    __half* __restrict__ H2, int N) {
  __shared__ __align__(16) unsigned char sY[16 * 64 * 2];
  __shared__ __align__(16) unsigned char sW[64 * 64 * 2];
  const int t = threadIdx.x;
  for (int idx = t; idx < 64 * 64; idx += 256) {
    int k = idx >> 6, n = idx & 63;
    __half h = __float2half_rn(W2[idx]);
    unsigned int off = (unsigned int)((n * 64 + k) * 2) ^ ((n & 7) << 4);
    *reinterpret_cast<unsigned short*>(sW + off) =
        *reinterpret_cast<unsigned short*>(&h);
  }

  const int wv = t >> 6;
  const int lane = t & 63;
  const int nid = lane >> 4;
  const int g = (lane >> 3) & 1;
  const int cl = lane & 7;
  const int nodeL = wv * 4 + nid;
  const int node = blockIdx.x * 16 + nodeL;
  const unsigned int choff = (unsigned int)cl << 4;
  const unsigned char* __restrict__ hb = (const unsigned char*)hs;
  int beg = 0, end = 0;
  if (node < N) {
    beg = rowptr[node];
    end = rowptr[node + 1];
  }
  __half2 accA[4] = {{0.f, 0.f}, {0.f, 0.f}, {0.f, 0.f}, {0.f, 0.f}};
  __half2 accB[4] = {{0.f, 0.f}, {0.f, 0.f}, {0.f, 0.f}, {0.f, 0.f}};
  int k = beg + g;
  while (k < end) {
    int s0 = esrc[min(k,     end - 1)];
    int s1 = esrc[min(k + 2, end - 1)];
    int s2 = esrc[min(k + 4, end - 1)];
    int s3 = esrc[min(k + 6, end - 1)];
    uint4 v0 = *reinterpret_cast<const uint4*>(hb + (((unsigned int)s0 << 7) + choff));
    uint4 v1 = *reinterpret_cast<const uint4*>(hb + (((unsigned int)s1 << 7) + choff));
    uint4 v2 = *reinterpret_cast<const uint4*>(hb + (((unsigned int)s2 << 7) + choff));
    uint4 v3 = *reinterpret_cast<const uint4*>(hb + (((unsigned int)s3 << 7) + choff));
    {
      accA[0] = h2add(accA[0], bcast_h2(v0.x));
      accA[1] = h2add(accA[1], bcast_h2(v0.y));
      accA[2] = h2add(accA[2], bcast_h2(v0.z));
      accA[3] = h2add(accA[3], bcast_h2(v0.w));
    }
    if (k + 2 < end) {
      accB[0] = h2add(accB[0], bcast_h2(v1.x));
      accB[1] = h2add(accB[1], bcast_h2(v1.y));
      accB[2] = h2add(accB[2], bcast_h2(v1.z));
      accB[3] = h2add(accB[3], bcast_h2(v1.w));
    }
    if (k + 4 < end) {
      accA[0] = h2add(accA[0], bcast_h2(v2.x));
      accA[1] = h2add(accA[1], bcast_h2(v2.y));
      accA[2] = h2add(accA[2], bcast_h2(v2.z));
      accA[3] = h2add(accA[3], bcast_h2(v2.w));
    }
    if (k + 6 < end) {
      accB[0] = h2add(accB[0], bcast_h2(v3.x));
      accB[1] = h2add(accB[1], bcast_h2(v3.y));
      accB[2] = h2add(accB[2], bcast_h2(v3.z));
      accB[3] = h2add(accB[3], bcast_h2(v3.w));
    }
    k += 8;
  }
#pragma unroll
  for (int r = 0; r < 4; ++r) accA[r] = h2add(accA[r], accB[r]);
#pragma unroll
  for (int r = 0; r < 4; ++r) {
    int u = __shfl_xor(*reinterpret_cast<int*>(&accA[r]), 8);
    accA[r] = h2add(accA[r], *reinterpret_cast<__half2*>(&u));
  }
  if (g == 0 && node < N) {
    uint4 sv = *reinterpret_cast<const uint4*>(hb + (((unsigned int)node << 7) + choff));
    float di = dinv[node];
    const float4* bv = reinterpret_cast<const float4*>(b);
    float4 b0 = bv[cl * 2], b1 = bv[cl * 2 + 1];
    float r[8];
#pragma unroll
    for (int q = 0; q < 4; ++q) {
      float2 av = __half22float2(accA[q]);
      float2 sf = __half22float2(bcast_h2((&sv.x)[q]));
      r[2 * q]     = (av.x + sf.x) * di;
      r[2 * q + 1] = (av.y + sf.y) * di;
    }
    r[0] += b0.x; r[1] += b0.y; r[2] += b0.z; r[3] += b0.w;
    r[4] += b1.x; r[5] += b1.y; r[6] += b1.z; r[7] += b1.w;
#pragma unroll
    for (int q = 0; q < 8; ++q) r[q] = fmaxf(r[q], 0.f);   // relu (layer 1)
    uint4 pk;
    pk.x = pack2(r[0], r[1]);
    pk.y = pack2(r[2], r[3]);
    pk.z = pack2(r[4], r[5]);
    pk.w = pack2(r[6], r[7]);
    unsigned int off = (unsigned int)((nodeL * 64 + cl * 8) * 2) ^ ((nodeL & 7) << 4);
    *reinterpret_cast<uint4*>(sY + off) = pk;
  }
  __syncthreads();
  if (wv == 0) {
    const int lr = lane & 15;
    const int lk = (lane >> 4) * 8;
    f32x4 acc[4] = {};
#pragma unroll
    for (int ks = 0; ks < 2; ++ks) {
      unsigned int aoff = (unsigned int)((lr * 64 + ks * 32 + lk) * 2) ^ ((lr & 7) << 4);
      f16x8 af = *reinterpret_cast<const f16x8*>(sY + aoff);
#pragma unroll
      for (int n = 0; n < 4; ++n) {
        int cc = n * 16 + lr;
        unsigned int boff = (unsigned int)((cc * 64 + ks * 32 + lk) * 2) ^ ((cc & 7) << 4);
        f16x8 bf = *reinterpret_cast<const f16x8*>(sW + boff);
        acc[n] = __builtin_amdgcn_mfma_f32_16x16x32_f16(af, bf, acc[n], 0, 0, 0);
      }
    }
#pragma unroll
    for (int j = 0; j < 4; ++j) {
      int rowL = (lane >> 4) * 4 + j;
      int row = blockIdx.x * 16 + rowL;
      if (row < N) {
        float di = dinv[row];
#pragma unroll
        for (int n = 0; n < 4; ++n) {
          float v = acc[n][j] * di;
          H2[(size_t)row * 64 + n * 16 + lr] = __float2half_rn(v);
        }
      }
    }
  }
}

// Final aggregation (layer 2): out fp32.
__global__ __launch_bounds__(256) void agg_kernel(const __half* __restrict__ hs,
                                                  const int* __restrict__ rowptr,
                                                  const int* __restrict__ esrc,
                                                  const float* __restrict__ dinv,
                                                  const float* __restrict__ b,
                                                  float* __restrict__ outv, int N) {
  const int wv = threadIdx.x >> 6;
  const int lane = threadIdx.x & 63;
  const int nid = lane >> 4;
  const int g = (lane >> 3) & 1;
  const int cl = lane & 7;
  const int node = blockIdx.x * 16 + wv * 4 + nid;
  const unsigned int choff = (unsigned int)cl << 4;
  const unsigned char* __restrict__ hb = (const unsigned char*)hs;
  int beg = 0, end = 0;
  if (node < N) {
    beg = rowptr[node];
    end = rowptr[node + 1];
  }
  __half2 accA[4] = {{0.f, 0.f}, {0.f, 0.f}, {0.f, 0.f}, {0.f, 0.f}};
  __half2 accB[4] = {{0.f, 0.f}, {0.f, 0.f}, {0.f, 0.f}, {0.f, 0.f}};
  int k = beg + g;
  while (k < end) {
    int s0 = esrc[min(k,     end - 1)];
    int s1 = esrc[min(k + 2, end - 1)];
    int s2 = esrc[min(k + 4, end - 1)];
    int s3 = esrc[min(k + 6, end - 1)];
    uint4 v0 = *reinterpret_cast<const uint4*>(hb + (((unsigned int)s0 << 7) + choff));
    uint4 v1 = *reinterpret_cast<const uint4*>(hb + (((unsigned int)s1 << 7) + choff));
    uint4 v2 = *reinterpret_cast<const uint4*>(hb + (((unsigned int)s2 << 7) + choff));
    uint4 v3 = *reinterpret_cast<const uint4*>(hb + (((unsigned int)s3 << 7) + choff));
    {
      accA[0] = h2add(accA[0], bcast_h2(v0.x));
      accA[1] = h2add(accA[1], bcast_h2(v0.y));
      accA[2] = h2add(accA[2], bcast_h2(v0.z));
      accA[3] = h2add(accA[3], bcast_h2(v0.w));
    }
    if (k + 2 < end) {
      accB[0] = h2add(accB[0], bcast_h2(v1.x));
      accB[1] = h2add(accB[1], bcast_h2(v1.y));
      accB[2] = h2add(accB[2], bcast_h2(v1.z));
      accB[3] = h2add(accB[3], bcast_h2(v1.w));
    }
    if (k + 4 < end) {
      accA[0] = h2add(accA[0], bcast_h2(v2.x));
      accA[1] = h2add(accA[1], bcast_h2(v2.y));
      accA[2] = h2add(accA[2], bcast_h2(v2.z));
      accA[3] = h2add(accA[3], bcast_h2(v2.w));
    }
    if (k + 6 < end) {
      accB[0] = h2add(accB[0], bcast_h2(v3.x));
      accB[1] = h2add(accB[1], bcast_h2(v3.y));
      accB[2] = h2add(accB[2], bcast_h2(v3.z));
      accB[3] = h2add(accB[3], bcast_h2(v3.w));
    }
    k += 8;
  }
#pragma unroll
  for (int r = 0; r < 4; ++r) accA[r] = h2add(accA[r], accB[r]);
#pragma unroll
  for (int r = 0; r < 4; ++r) {
    int u = __shfl_xor(*reinterpret_cast<int*>(&accA[r]), 8);
    accA[r] = h2add(accA[r], *reinterpret_cast<__half2*>(&u));
  }
  if (g == 0 && node < N) {
    uint4 sv = *reinterpret_cast<const uint4*>(hb + (((unsigned int)node << 7) + choff));
    float di = dinv[node];
    const float4* bv = reinterpret_cast<const float4*>(b);
    float4 b0 = bv[cl * 2], b1 = bv[cl * 2 + 1];
    float r[8];
#pragma unroll
    for (int q = 0; q < 4; ++q) {
      float2 av = __half22float2(accA[q]);
      float2 sf = __half22float2(bcast_h2((&sv.x)[q]));
      r[2 * q]     = (av.x + sf.x) * di;
      r[2 * q + 1] = (av.y + sf.y) * di;
    }
    r[0] += b0.x; r[1] += b0.y; r[2] += b0.z; r[3] += b0.w;
    r[4] += b1.x; r[5] += b1.y; r[6] += b1.z; r[7] += b1.w;
    float4* ov = reinterpret_cast<float4*>(outv);
    ov[(size_t)node * 16 + cl * 2]     = make_float4(r[0], r[1], r[2], r[3]);
    ov[(size_t)node * 16 + cl * 2 + 1] = make_float4(r[4], r[5], r[6], r[7]);
  }
}

extern "C" void kernel_launch(void* const* d_in, const int* in_sizes, int n_in,
                              void* d_out, int out_size, void* d_ws, size_t ws_size,
                              hipStream_t stream) {
  const float* x  = (const float*)d_in[0];
  const int*   ei = (const int*)d_in[1];
  const float* W1 = (const float*)d_in[2];
  const float* b1 = (const float*)d_in[3];
  const float* W2 = (const float*)d_in[4];
  const float* b2 = (const float*)d_in[5];
  const int N = in_sizes[0] / 128;
  const int E = in_sizes[1] / 2;
  const int* src = ei;
  const int* dst = ei + E;
  const int nb = (N + 255) >> BSHIFT;  // 391 buckets of 256 nodes

  char* ws = (char*)d_ws;
  int*    bcursor = (int*)ws;                       // nb ints
  float*  dinv    = (float*)(ws + (1 << 20));       // N floats  @ 1MB
  int*    rowptr  = (int*)(ws + 3 * (1 << 19));     // N+1 ints  @ 1.5MB
  int*    esrc    = (int*)(ws + (1 << 21));         // E ints    @ 2MB   (6.4MB)
  int*    ebuck   = (int*)(ws + 9 * (1 << 20));     // nb*BCAP   @ 9MB   (12.8MB)
  __half* hs      = (__half*)(ws + 22 * (1 << 20)); // N*64 fp16 @ 22MB  (12.8MB)
  __half* hs2     = (__half*)(ws + 36 * (1 << 20)); // N*64 fp16 @ 36MB  (12.8MB)
  float*  out = (float*)d_out;

  // CSR build (shared by both layers)
  initcur_kernel<<<(nb + 255) / 256, 256, 0, stream>>>(bcursor, nb);
  chunksort_kernel<<<(E + CHUNK - 1) / CHUNK, 1024, 0, stream>>>(src, dst, bcursor,
                                                                 ebuck, E, nb);
  bucketsort_kernel<<<nb, 1024, 0, stream>>>(ebuck, bcursor, esrc, rowptr,
                                             dinv, N, E, nb);

  const int gemmGrid = (N + 63) / 64;
  const int aggGrid = (N + 15) / 16;
  // layer 1 GEMM: hs1(fp16) -> hs
  gemm_mfma<128><<<gemmGrid, 256, 0, stream>>>(x, W1, dinv, hs, N);
  // fused layer-1 aggregation + layer-2 GEMM: hs2(fp16)
  agg_gemm_kernel<<<aggGrid, 256, 0, stream>>>(hs, rowptr, esrc, dinv, b1, W2,
                                               hs2, N);
  // layer-2 aggregation: out fp32
  agg_kernel<<<aggGrid, 256, 0, stream>>>(hs2, rowptr, esrc, dinv, b2, out, N);
}